// Round 17
// baseline (491.545 us; speedup 1.0000x reference)
//
#include <hip/hip_runtime.h>
#include <hip/hip_bf16.h>
#include <math.h>

// ---------------------------------------------------------------------------
// ELAN + SwinV2: bf16 MFMA convs + GEMMs; fused qkv+attention v6 (3 blocks/CU:
// 2-round K/Q transpose scratch, Ol bounce overlaid on dead Elds, float2 bias
// pairs); mlp2+LN2 fused. B=4, C_IN=128, H=W=128, DIM=256, WS=8, HEADS=8.
// ---------------------------------------------------------------------------

#define HW 16384
typedef unsigned int u32;
typedef unsigned short u16;
typedef __attribute__((ext_vector_type(8))) short short8;   // bf16x8 MFMA frag
typedef __attribute__((ext_vector_type(4))) float floatx4;  // f32x4 acc frag

// compiler-only fence: blocks LDS load/store reordering (HW is in-order per wave)
#define MEMBAR() asm volatile("" ::: "memory")

__device__ __forceinline__ float silu_f(float y) { return y / (1.f + expf(-y)); }
__device__ __forceinline__ float bflo(u32 u) { return __uint_as_float(u << 16); }
__device__ __forceinline__ float bfhi(u32 u) { return __uint_as_float(u & 0xffff0000u); }
__device__ __forceinline__ float bf2f(u16 v) { return __uint_as_float((u32)v << 16); }
__device__ __forceinline__ u16 f2bf(float x) {
  u32 u = __float_as_uint(x);
  u += 0x7fffu + ((u >> 16) & 1u);
  return (u16)(u >> 16);
}
__device__ __forceinline__ u32 pack2(float a, float b) {
  return (u32)f2bf(a) | ((u32)f2bf(b) << 16);
}
__device__ __forceinline__ short8 mk8(u32 a, u32 b, u32 c, u32 d) {
  union { u32 u[4]; short8 s; } t;
  t.u[0] = a; t.u[1] = b; t.u[2] = c; t.u[3] = d;
  return t.s;
}
// both shfls executed by all lanes (uniform), then per-lane select
__device__ __forceinline__ u32 shfl_sel(u32 va, u32 vb, int s, bool sel) {
  u32 x = (u32)__shfl((int)va, s);
  u32 y = (u32)__shfl((int)vb, s);
  return sel ? y : x;
}

#define GLDS16(gp, lp)                                           \
  __builtin_amdgcn_global_load_lds(                              \
      (const __attribute__((address_space(1))) void*)(gp),       \
      (__attribute__((address_space(3))) void*)(lp), 16, 0, 0)

// ---------------- unified prep: conv/stem repack + qkv/proj/mlp casts -------
__global__ __launch_bounds__(256) void prep_kernel(
    const float* __restrict__ w_blk, const float* __restrict__ s_blk,
    const float* __restrict__ w_stem, const float* __restrict__ s_stem,
    const float* __restrict__ qkv_w, const float* __restrict__ proj_w,
    const float* __restrict__ mlp_w1, const float* __restrict__ mlp_w2,
    u16* __restrict__ wtc, u16* __restrict__ wts, u16* __restrict__ qwb,
    u16* __restrict__ pwb, u16* __restrict__ m1wb, u16* __restrict__ m2wb) {
  int idx = blockIdx.x * 256 + threadIdx.x;
  if (idx < 147456) {
    int c = idx & 63;
    int rest = idx >> 6;
    int oc = rest & 63;
    int ct = rest >> 6;
    int conv = ct / 9, t = ct % 9;
    float w = w_blk[((size_t)(conv * 64 + oc) * 64 + c) * 9 + t];
    wtc[idx] = f2bf(w * s_blk[conv * 64 + oc]);
  } else if (idx < 163840) {
    int j = idx - 147456;
    int c = j & 127, oc = j >> 7;
    wts[j] = f2bf(w_stem[(size_t)oc * 128 + c] * s_stem[oc]);
  } else if (idx < 360448) {
    int j = idx - 163840;
    qwb[j] = f2bf(qkv_w[j]);
  } else if (idx < 425984) {
    int j = idx - 360448;
    pwb[j] = f2bf(proj_w[j]);
  } else if (idx < 491520) {
    int j = idx - 425984;
    m1wb[j] = f2bf(mlp_w1[j]);
  } else if (idx < 557056) {
    int j = idx - 491520;
    m2wb[j] = f2bf(mlp_w2[j]);
  }
}

// ---------------- continuous position bias MLP -----------------------------
__global__ __launch_bounds__(512) void cpb_mlp_kernel(
    const float* __restrict__ w1, const float* __restrict__ b1,
    const float* __restrict__ w2, float* __restrict__ pre) {
  __shared__ float hb[512];
  int t = blockIdx.x, j = threadIdx.x;
  int i = t / 15, jj = t % 15;
  float c0 = (float)(i - 7) * (8.f / 7.f);
  float c1 = (float)(jj - 7) * (8.f / 7.f);
  float s0 = (c0 > 0.f) ? 1.f : ((c0 < 0.f) ? -1.f : 0.f);
  float s1 = (c1 > 0.f) ? 1.f : ((c1 < 0.f) ? -1.f : 0.f);
  float t0 = s0 * log2f(fabsf(c0) + 1.f) * (1.f / 3.f);
  float t1 = s1 * log2f(fabsf(c1) + 1.f) * (1.f / 3.f);
  float h = t0 * w1[j * 2] + t1 * w1[j * 2 + 1] + b1[j];
  hb[j] = fmaxf(h, 0.f);
  __syncthreads();
  if (j < 8) {
    float s = 0.f;
    for (int k = 0; k < 512; ++k) s += hb[k] * w2[j * 512 + k];
    pre[t * 8 + j] = s;
  }
}

// bias_t2[h][m>>1][n][m&1]: row-pair float2 layout (4096 floats/head)
__global__ __launch_bounds__(256) void cpb_expand_kernel(
    const float* __restrict__ pre, float* __restrict__ bias_t) {
  int idx = blockIdx.x * 256 + threadIdx.x;
  int m = idx >> 6, n = idx & 63;
  int di = (n >> 3) - (m >> 3) + 7;
  int dj = (n & 7) - (m & 7) + 7;
  int ti = di * 15 + dj;
#pragma unroll
  for (int h = 0; h < 8; ++h) {
    float v = pre[ti * 8 + h];
    bias_t[h * 4096 + (((m >> 1) * 64 + n) << 1) + (m & 1)] =
        16.f / (1.f + expf(-v));
  }
}

// ---------------- x NCHW fp32 -> XT NHWC bf16 -------------------------------
__global__ __launch_bounds__(256) void transpose_in_kernel(
    const float* __restrict__ x, u16* __restrict__ xt) {
  __shared__ float tl[64][65];
  int bid = blockIdx.x;
  int b = bid >> 9;
  int r = bid & 511;
  int cs = r >> 8, hws = r & 255;
  int c0 = cs << 6, hw0 = hws << 6;
  int tid = threadIdx.x;
  for (int e = tid; e < 4096; e += 256) {
    int c = e >> 6, p = e & 63;
    tl[c][p] = x[(size_t)(b * 128 + c0 + c) * HW + hw0 + p];
  }
  __syncthreads();
  for (int e = tid; e < 4096; e += 256) {
    int p = e >> 6, c = e & 63;
    xt[(size_t)(b * HW + hw0 + p) * 128 + c0 + c] = f2bf(tl[c][p]);
  }
}

// ---------------- bf16 MFMA GEMM: C[.,col]=act(A[M,K] @ W[N,K]^T + b) -------
__global__ __launch_bounds__(256, 4) void gemm_bf16_kernel(
    const u16* __restrict__ A, const u16* __restrict__ W,
    const float* __restrict__ bias, u16* __restrict__ C, int K, int ldc,
    int act) {
  __shared__ u16 As[128 * 64];
  __shared__ u16 Ws[64 * 64];
  int tid = threadIdx.x;
  int wv = tid >> 6, lane = tid & 63;
  int m0 = blockIdx.y * 128, n0 = blockIdx.x * 64;
  floatx4 zz = {0.f, 0.f, 0.f, 0.f};
  floatx4 acc[2][4];
#pragma unroll
  for (int i = 0; i < 2; ++i)
#pragma unroll
    for (int j = 0; j < 4; ++j) acc[i][j] = zz;
  int lr = lane >> 3, ls = lane & 7;
  for (int k0 = 0; k0 < K; k0 += 64) {
#pragma unroll
    for (int i = 0; i < 4; ++i) {
      int ci = wv * 4 + i;
      int r = ci * 8 + lr;
      int cc = ls ^ (r & 7);
      GLDS16(A + (size_t)(m0 + r) * K + k0 + cc * 8, As + ci * 512);
    }
#pragma unroll
    for (int i = 0; i < 2; ++i) {
      int ci = wv * 2 + i;
      int r = ci * 8 + lr;
      int cc = ls ^ (r & 7);
      GLDS16(W + (size_t)(n0 + r) * K + k0 + cc * 8, Ws + ci * 512);
    }
    __syncthreads();
#pragma unroll
    for (int kk = 0; kk < 2; ++kk) {
      int g = kk * 4 + (lane >> 4);
      short8 a0, a1, b0, b1, b2, b3;
      {
        int row = wv * 32 + (lane & 15);
        a0 = *(const short8*)&As[row * 64 + (g ^ (row & 7)) * 8];
        int row2 = row + 16;
        a1 = *(const short8*)&As[row2 * 64 + (g ^ (row2 & 7)) * 8];
      }
      {
        int col = lane & 15;
        b0 = *(const short8*)&Ws[col * 64 + (g ^ (col & 7)) * 8];
        int c1 = col + 16;
        b1 = *(const short8*)&Ws[c1 * 64 + (g ^ (c1 & 7)) * 8];
        int c2 = col + 32;
        b2 = *(const short8*)&Ws[c2 * 64 + (g ^ (c2 & 7)) * 8];
        int c3 = col + 48;
        b3 = *(const short8*)&Ws[c3 * 64 + (g ^ (c3 & 7)) * 8];
      }
      acc[0][0] = __builtin_amdgcn_mfma_f32_16x16x32_bf16(a0, b0, acc[0][0], 0, 0, 0);
      acc[0][1] = __builtin_amdgcn_mfma_f32_16x16x32_bf16(a0, b1, acc[0][1], 0, 0, 0);
      acc[0][2] = __builtin_amdgcn_mfma_f32_16x16x32_bf16(a0, b2, acc[0][2], 0, 0, 0);
      acc[0][3] = __builtin_amdgcn_mfma_f32_16x16x32_bf16(a0, b3, acc[0][3], 0, 0, 0);
      acc[1][0] = __builtin_amdgcn_mfma_f32_16x16x32_bf16(a1, b0, acc[1][0], 0, 0, 0);
      acc[1][1] = __builtin_amdgcn_mfma_f32_16x16x32_bf16(a1, b1, acc[1][1], 0, 0, 0);
      acc[1][2] = __builtin_amdgcn_mfma_f32_16x16x32_bf16(a1, b2, acc[1][2], 0, 0, 0);
      acc[1][3] = __builtin_amdgcn_mfma_f32_16x16x32_bf16(a1, b3, acc[1][3], 0, 0, 0);
    }
    __syncthreads();
  }
  int rbase = wv * 32 + ((lane >> 4) << 2);
  int cb = lane & 15;
#pragma unroll
  for (int mi = 0; mi < 2; ++mi) {
#pragma unroll
    for (int nj = 0; nj < 4; ++nj) {
      int col = n0 + nj * 16 + cb;
      float bv = bias[col];
#pragma unroll
      for (int r = 0; r < 4; ++r) {
        int row = m0 + rbase + mi * 16 + r;
        float v = acc[mi][nj][r] + bv;
        if (act == 1) v = 0.5f * v * (1.f + erff(v * 0.70710678118654752f));
        else if (act == 2) v = silu_f(v);
        C[(size_t)row * ldc + col] = f2bf(v);
      }
    }
  }
}

// ---------------- 3x3 conv 64->64 pad1 SiLU, NHWC bf16, implicit MFMA GEMM --
__global__ __launch_bounds__(256) void conv3x3_mfma_kernel(
    const u16* __restrict__ in, int istr, u16* __restrict__ outp, int ostr,
    const u16* __restrict__ wt, const float* __restrict__ bias) {
  __shared__ u16 tile[6400];
  int tid = threadIdx.x;
  int wv = tid >> 6, lane = tid & 63;
  int bx = blockIdx.x, by = blockIdx.y, b = blockIdx.z;
  int h0 = by * 8, w0 = bx * 8;
#pragma unroll
  for (int rr = 0; rr < 4; ++rr) {
    int slot = rr * 256 + tid;
    int p = slot >> 3, ch = slot & 7;
    if (p < 100) {
      int hr = p / 10, hc = p % 10;
      int gh = h0 + hr - 1, gw = w0 + hc - 1;
      bool ok = (gh >= 0) && (gh < 128) && (gw >= 0) && (gw < 128);
      uint4 v = {0u, 0u, 0u, 0u};
      if (ok) {
        size_t pix = (size_t)((b * 128 + gh) * 128 + gw);
        v = *(const uint4*)(in + pix * istr + ch * 8);
      }
      *(uint4*)(tile + p * 64 + ((ch ^ (p & 7)) << 3)) = v;
    }
  }
  __syncthreads();
  int pl = lane & 15;
  int g = lane >> 4;
  int prow = 2 * wv + (pl >> 3), pcol = pl & 7;
  floatx4 zz = {0.f, 0.f, 0.f, 0.f};
  floatx4 acc[4] = {zz, zz, zz, zz};
#pragma unroll
  for (int t = 0; t < 9; ++t) {
    int dy = t / 3, dx = t % 3;
    int hp = (prow + dy) * 10 + (pcol + dx);
    short8 bf0 = *(const short8*)&tile[hp * 64 + (((0 * 4 + g) ^ (hp & 7)) << 3)];
    short8 bf1 = *(const short8*)&tile[hp * 64 + (((1 * 4 + g) ^ (hp & 7)) << 3)];
    const u16* wtap = wt + t * 4096;
#pragma unroll
    for (int nf = 0; nf < 4; ++nf) {
      short8 a0 = *(const short8*)&wtap[(nf * 16 + pl) * 64 + g * 8];
      short8 a1 = *(const short8*)&wtap[(nf * 16 + pl) * 64 + 32 + g * 8];
      acc[nf] = __builtin_amdgcn_mfma_f32_16x16x32_bf16(a0, bf0, acc[nf], 0, 0, 0);
      acc[nf] = __builtin_amdgcn_mfma_f32_16x16x32_bf16(a1, bf1, acc[nf], 0, 0, 0);
    }
  }
  size_t pix = (size_t)((b * 128 + h0 + prow) * 128 + w0 + pcol);
#pragma unroll
  for (int nf = 0; nf < 4; ++nf) {
    float o0 = silu_f(acc[nf][0] + bias[nf * 16 + g * 4 + 0]);
    float o1 = silu_f(acc[nf][1] + bias[nf * 16 + g * 4 + 1]);
    float o2 = silu_f(acc[nf][2] + bias[nf * 16 + g * 4 + 2]);
    float o3 = silu_f(acc[nf][3] + bias[nf * 16 + g * 4 + 3]);
    uint2 w2;
    w2.x = pack2(o0, o1);
    w2.y = pack2(o2, o3);
    *(uint2*)(outp + pix * ostr + nf * 16 + g * 4) = w2;
  }
}

// ---------------- fused qkv-GEMM + window attention v6 ----------------------
// block = 1 window x 8 heads (512 thr, wave = head). E staged once (32KB).
// Per-wave 2.5KB scratch: K/Q transposed in two 32-row rounds. Ol bounce
// overlays dead Elds after barrier #2. LDS 52KB -> 3 blocks/CU.
__device__ __forceinline__ void qkv_mm(const u16* Elds, const u16* qwb,
                                       int moff, int h, int lc, int lg,
                                       floatx4 acc[4][2]) {
  floatx4 zz = {0.f, 0.f, 0.f, 0.f};
#pragma unroll
  for (int mf = 0; mf < 4; ++mf) {
    acc[mf][0] = zz;
    acc[mf][1] = zz;
  }
#pragma unroll
  for (int ks = 0; ks < 8; ++ks) {
    int ch = ks >> 1, g = ((ks & 1) << 2) + lg;
    short8 af[4];
#pragma unroll
    for (int mf = 0; mf < 4; ++mf) {
      int tk = mf * 16 + lc;
      af[mf] = *(const short8*)&Elds[(ch * 64 + tk) * 64 + ((g ^ (tk & 7)) << 3)];
    }
#pragma unroll
    for (int nf = 0; nf < 2; ++nf) {
      short8 bf = *(const short8*)(qwb +
          (size_t)(moff + h * 32 + nf * 16 + lc) * 256 + ks * 32 + lg * 8);
#pragma unroll
      for (int mf = 0; mf < 4; ++mf)
        acc[mf][nf] =
            __builtin_amdgcn_mfma_f32_16x16x32_bf16(af[mf], bf, acc[mf][nf], 0, 0, 0);
    }
  }
}

__global__ __launch_bounds__(512, 6) void attn_fused_kernel(
    const u16* __restrict__ ebf, const u16* __restrict__ qwb,
    const float* __restrict__ qkv_b, const float* __restrict__ logit_scale,
    const float* __restrict__ bias_t, u16* __restrict__ ao) {
  __shared__ __align__(16) char lds[53248];
  int tid = threadIdx.x;
  int w = tid >> 6, l = tid & 63;
  int wid = blockIdx.x;
  int h = __builtin_amdgcn_readfirstlane(w);
  u16* Elds = (u16*)lds;              // [4 chunks][64 rows][64] swizzled (32KB)
  char* Sc = lds + 32768 + w * 2560;  // per-wave scratch [32 rows][80B]

  int b = wid >> 8, wh = (wid >> 4) & 15, ww = wid & 15;
  int pixbase = (b << 14) + wh * 1024 + ww * 8;
  {  // stage E window once: wave w stages half of chunk w>>1
    int lr = l >> 3, ls = l & 7;
    int ch = w >> 1;
#pragma unroll
    for (int j = 0; j < 4; ++j) {
      int jj = ((w & 1) << 2) + j;
      int pix = pixbase + jj * 128 + lr;
      GLDS16(ebf + (size_t)pix * 256 + ch * 64 + ((ls ^ lr) << 3),
             Elds + (ch * 8 + jj) * 512);
    }
  }
  __syncthreads();  // barrier #1: E staged

  int lc = l & 15, lg = l >> 4;
  float scale = __expf(fminf(logit_scale[h], 4.6051701860f));
  floatx4 macc[4][2];
  short8 kf[4], qf[4];

  // ---- K: project, normalize; transpose via 32-row scratch, 2 rounds ----
  qkv_mm(Elds, qwb, 256, h, lc, lg, macc);
#pragma unroll
  for (int half = 0; half < 2; ++half) {
#pragma unroll
    for (int mf2 = 0; mf2 < 2; ++mf2) {
      int mf = half * 2 + mf2;
#pragma unroll
      for (int r = 0; r < 4; ++r) {
        float v0 = macc[mf][0][r], v1 = macc[mf][1][r];
        float ss = v0 * v0 + v1 * v1;
        ss += __shfl_xor(ss, 1);
        ss += __shfl_xor(ss, 2);
        ss += __shfl_xor(ss, 4);
        ss += __shfl_xor(ss, 8);
        float rk = 1.f / fmaxf(sqrtf(ss), 1e-12f);
        int tk = mf2 * 16 + (lg << 2) + r;
        *(u16*)(Sc + tk * 80 + lc * 2) = f2bf(v0 * rk);
        *(u16*)(Sc + tk * 80 + (16 + lc) * 2) = f2bf(v1 * rk);
      }
    }
    MEMBAR();
#pragma unroll
    for (int i = 0; i < 2; ++i)
      kf[half * 2 + i] = *(const short8*)(Sc + (i * 16 + lc) * 80 + (lg << 4));
    MEMBAR();
  }

  // ---- Q: project+bias, normalize*scale; 2-round transpose -> qf ----
  qkv_mm(Elds, qwb, 0, h, lc, lg, macc);
  {
    float qb0 = qkv_b[h * 32 + lc], qb1 = qkv_b[h * 32 + 16 + lc];
#pragma unroll
    for (int half = 0; half < 2; ++half) {
#pragma unroll
      for (int mf2 = 0; mf2 < 2; ++mf2) {
        int mf = half * 2 + mf2;
#pragma unroll
        for (int r = 0; r < 4; ++r) {
          float v0 = macc[mf][0][r] + qb0, v1 = macc[mf][1][r] + qb1;
          float ss = v0 * v0 + v1 * v1;
          ss += __shfl_xor(ss, 1);
          ss += __shfl_xor(ss, 2);
          ss += __shfl_xor(ss, 4);
          ss += __shfl_xor(ss, 8);
          float rq = scale / fmaxf(sqrtf(ss), 1e-12f);
          int tk = mf2 * 16 + (lg << 2) + r;
          *(u16*)(Sc + tk * 80 + lc * 2) = f2bf(v0 * rq);
          *(u16*)(Sc + tk * 80 + (16 + lc) * 2) = f2bf(v1 * rq);
        }
      }
      MEMBAR();
#pragma unroll
      for (int i = 0; i < 2; ++i)
        qf[half * 2 + i] = *(const short8*)(Sc + (i * 16 + lc) * 80 + (lg << 4));
      MEMBAR();
    }
  }

  // ---- V: project + bias, pack bf16 pairs in regs ----
  u32 v01[4][2], v23[4][2];
  qkv_mm(Elds, qwb, 512, h, lc, lg, macc);
  {
    float vb0 = qkv_b[512 + h * 32 + lc], vb1 = qkv_b[512 + h * 32 + 16 + lc];
#pragma unroll
    for (int mf = 0; mf < 4; ++mf) {
      v01[mf][0] = pack2(macc[mf][0][0] + vb0, macc[mf][0][1] + vb0);
      v23[mf][0] = pack2(macc[mf][0][2] + vb0, macc[mf][0][3] + vb0);
      v01[mf][1] = pack2(macc[mf][1][0] + vb1, macc[mf][1][1] + vb1);
      v23[mf][1] = pack2(macc[mf][1][2] + vb1, macc[mf][1][3] + vb1);
    }
  }

  // ---- S^T = Kn @ Qs^T ----
  floatx4 zz = {0.f, 0.f, 0.f, 0.f};
  floatx4 S[4][4];
#pragma unroll
  for (int mi = 0; mi < 4; ++mi)
#pragma unroll
    for (int ni = 0; ni < 4; ++ni)
      S[mi][ni] = __builtin_amdgcn_mfma_f32_16x16x32_bf16(kf[mi], qf[ni], zz, 0, 0, 0);

  // softmax: bias loaded as row-pair float2 (identical values, half the loads)
  const float* bh = bias_t + h * 4096;
  float den[4] = {0.f, 0.f, 0.f, 0.f};
#pragma unroll
  for (int mi = 0; mi < 4; ++mi) {
#pragma unroll
    for (int r2 = 0; r2 < 2; ++r2) {
      int m2 = mi * 8 + (lg << 1) + r2;
#pragma unroll
      for (int ni = 0; ni < 4; ++ni) {
        int nn = ni * 16 + lc;
        float2 bp = *(const float2*)(bh + ((m2 * 64 + nn) << 1));
        float e0 = __expf(S[mi][ni][2 * r2] + bp.x);
        float e1 = __expf(S[mi][ni][2 * r2 + 1] + bp.y);
        S[mi][ni][2 * r2] = e0;
        S[mi][ni][2 * r2 + 1] = e1;
        den[ni] += e0 + e1;
      }
    }
  }
#pragma unroll
  for (int ni = 0; ni < 4; ++ni) {
    den[ni] += __shfl_xor(den[ni], 16);
    den[ni] += __shfl_xor(den[ni], 32);
    den[ni] = 1.f / den[ni];
  }
  // P packs (inv folded): p01/p23[mi][ni] hold rows m=mi*16+lg*4+{0,1}/{2,3}
  u32 p01[4][4], p23[4][4];
#pragma unroll
  for (int mi = 0; mi < 4; ++mi)
#pragma unroll
    for (int ni = 0; ni < 4; ++ni) {
      p01[mi][ni] = pack2(S[mi][ni][0] * den[ni], S[mi][ni][1] * den[ni]);
      p23[mi][ni] = pack2(S[mi][ni][2] * den[ni], S[mi][ni][3] * den[ni]);
    }

  // ---- lg-quarter exchange: build V frags and P frags in-register ----
  int s1 = ((lg & 1) << 5) + lc;  // source lane (lg_s=(lg&1)*2, lc)
  int s2 = s1 + 16;
  bool hi = lg >= 2;              // selects odd mf/mi candidate
  short8 vf[2][2];
#pragma unroll
  for (int ks = 0; ks < 2; ++ks)
#pragma unroll
    for (int db = 0; db < 2; ++db) {
      u32 w0 = shfl_sel(v01[ks * 2][db], v01[ks * 2 + 1][db], s1, hi);
      u32 w1 = shfl_sel(v23[ks * 2][db], v23[ks * 2 + 1][db], s1, hi);
      u32 w2 = shfl_sel(v01[ks * 2][db], v01[ks * 2 + 1][db], s2, hi);
      u32 w3 = shfl_sel(v23[ks * 2][db], v23[ks * 2 + 1][db], s2, hi);
      vf[ks][db] = mk8(w0, w1, w2, w3);
    }
  floatx4 O[4][2];
#pragma unroll
  for (int nb = 0; nb < 4; ++nb) {
    u32 a0 = shfl_sel(p01[0][nb], p01[1][nb], s1, hi);
    u32 a1 = shfl_sel(p23[0][nb], p23[1][nb], s1, hi);
    u32 a2 = shfl_sel(p01[0][nb], p01[1][nb], s2, hi);
    u32 a3 = shfl_sel(p23[0][nb], p23[1][nb], s2, hi);
    short8 pf0 = mk8(a0, a1, a2, a3);
    u32 b0 = shfl_sel(p01[2][nb], p01[3][nb], s1, hi);
    u32 b1 = shfl_sel(p23[2][nb], p23[3][nb], s1, hi);
    u32 b2 = shfl_sel(p01[2][nb], p01[3][nb], s2, hi);
    u32 b3 = shfl_sel(p23[2][nb], p23[3][nb], s2, hi);
    short8 pf1 = mk8(b0, b1, b2, b3);
    floatx4 o0 = __builtin_amdgcn_mfma_f32_16x16x32_bf16(pf0, vf[0][0], zz, 0, 0, 0);
    o0 = __builtin_amdgcn_mfma_f32_16x16x32_bf16(pf1, vf[1][0], o0, 0, 0, 0);
    floatx4 o1 = __builtin_amdgcn_mfma_f32_16x16x32_bf16(pf0, vf[0][1], zz, 0, 0, 0);
    o1 = __builtin_amdgcn_mfma_f32_16x16x32_bf16(pf1, vf[1][1], o1, 0, 0, 0);
    O[nb][0] = o0;
    O[nb][1] = o1;
  }

  // ---- barrier #2: all E reads done; Elds becomes per-wave Ol bounce ----
  __syncthreads();
  char* Ol = lds + (w << 12);  // 4KB/wave, rows of 64B (no pad)
#pragma unroll
  for (int nb = 0; nb < 4; ++nb)
#pragma unroll
    for (int r = 0; r < 4; ++r) {
      int n = nb * 16 + (lg << 2) + r;
      *(u16*)(Ol + n * 64 + lc * 2) = f2bf(O[nb][0][r]);
      *(u16*)(Ol + n * 64 + (16 + lc) * 2) = f2bf(O[nb][1][r]);
    }
  MEMBAR();
  u32 ov[16];
#pragma unroll
  for (int j = 0; j < 16; ++j) ov[j] = *(const u32*)(Ol + l * 64 + j * 4);
  uint4* op = (uint4*)(ao + (size_t)(wid * 64 + l) * 256 + h * 32);
#pragma unroll
  for (int q4 = 0; q4 < 4; ++q4) {
    uint4 v;
    v.x = ov[q4 * 4 + 0];
    v.y = ov[q4 * 4 + 1];
    v.z = ov[q4 * 4 + 2];
    v.w = ov[q4 * 4 + 3];
    op[q4] = v;
  }
}

// ---------------- LN1: SBF = bf16( EBF + LN(P) ), vectorized (R4) -----------
__global__ __launch_bounds__(256) void ln1v_kernel(
    const u16* __restrict__ pin, const u16* __restrict__ ebf,
    u16* __restrict__ sbf, const float* __restrict__ g,
    const float* __restrict__ bb) {
  int tid = threadIdx.x;
  int bid = blockIdx.x;  // 1024 = b(4) x 256 groups of 64 pixels
  int b = bid >> 8, hw0 = (bid & 255) << 6;
  int i = tid >> 2, qq = tid & 3;
  int hw = hw0 + i;
  int him = hw >> 7, wim = hw & 127;
  int wid = b * 256 + (him >> 3) * 16 + (wim >> 3);
  int t = wid * 64 + (him & 7) * 8 + (wim & 7);
  size_t pbase = (size_t)t * 256 + qq * 64;
  size_t ebase = ((size_t)(b * HW + hw)) * 256 + qq * 64;
  float v[64];
  float s1 = 0.f, s2 = 0.f;
#pragma unroll
  for (int j = 0; j < 8; ++j) {
    uint4 u = *(const uint4*)(pin + pbase + j * 8);
    u32 ua[4] = {u.x, u.y, u.z, u.w};
#pragma unroll
    for (int k = 0; k < 4; ++k) {
      float a = bflo(ua[k]), c = bfhi(ua[k]);
      v[j * 8 + 2 * k] = a;
      v[j * 8 + 2 * k + 1] = c;
      s1 += a + c;
      s2 += a * a + c * c;
    }
  }
  s1 += __shfl_xor(s1, 1);
  s1 += __shfl_xor(s1, 2);
  s2 += __shfl_xor(s2, 1);
  s2 += __shfl_xor(s2, 2);
  float mean = s1 * (1.f / 256.f);
  float var = s2 * (1.f / 256.f) - mean * mean;
  float rs = rsqrtf(var + 1e-5f);
#pragma unroll
  for (int j = 0; j < 8; ++j) {
    uint4 u = *(const uint4*)(ebf + ebase + j * 8);
    u32 ua[4] = {u.x, u.y, u.z, u.w};
    uint4 o;
    u32 ow[4];
#pragma unroll
    for (int k = 0; k < 4; ++k) {
      int c = qq * 64 + j * 8 + 2 * k;
      float o0 = bflo(ua[k]) + (v[j * 8 + 2 * k] - mean) * rs * g[c] + bb[c];
      float o1 = bfhi(ua[k]) + (v[j * 8 + 2 * k + 1] - mean) * rs * g[c + 1] + bb[c + 1];
      ow[k] = pack2(o0, o1);
    }
    o.x = ow[0]; o.y = ow[1]; o.z = ow[2]; o.w = ow[3];
    *(uint4*)(sbf + ebase + j * 8) = o;
  }
}

// ---------------- fused mlp2-GEMM (64x256,K=256) + LN2 + residual + NCHW ----
// rows = pixels (no remap). A=Hb, res=SBF, out = NCHW fp32 final output.
__global__ __launch_bounds__(256, 4) void gemm_ln2_kernel(
    const u16* __restrict__ A, const u16* __restrict__ W,
    const float* __restrict__ bias, const float* __restrict__ g,
    const float* __restrict__ bb, const u16* __restrict__ res,
    float* __restrict__ outf) {
  __shared__ __align__(16) char lds[40960];
  u16* As = (u16*)lds;            // [64][64] per k-chunk
  u16* Ws = (u16*)(lds + 8192);   // [256][64]
  u16* Ct = (u16*)lds;            // overlay [64][264]
  int tid = threadIdx.x;
  int w = tid >> 6, l = tid & 63;
  int lr = l >> 3, ls = l & 7;
  int lc = l & 15, lg = l >> 4;
  int m0 = blockIdx.x << 6;
  floatx4 zz = {0.f, 0.f, 0.f, 0.f};
  floatx4 acc[16];
#pragma unroll
  for (int i = 0; i < 16; ++i) acc[i] = zz;
  for (int k0 = 0; k0 < 256; k0 += 64) {
#pragma unroll
    for (int j = 0; j < 2; ++j) {
      int ci = w * 2 + j;
      int r = ci * 8 + lr;
      GLDS16(A + (size_t)(m0 + r) * 256 + k0 + ((ls ^ (r & 7)) << 3),
             As + ci * 512);
    }
#pragma unroll
    for (int j = 0; j < 8; ++j) {
      int ci = w * 8 + j;
      int r = ci * 8 + lr;
      GLDS16(W + (size_t)r * 256 + k0 + ((ls ^ (r & 7)) << 3), Ws + ci * 512);
    }
    __syncthreads();
#pragma unroll
    for (int kk = 0; kk < 2; ++kk) {
      int gg = (kk << 2) + lg;
      int arow = w * 16 + lc;
      short8 af = *(const short8*)&As[arow * 64 + ((gg ^ (arow & 7)) << 3)];
#pragma unroll
      for (int nf = 0; nf < 16; ++nf) {
        int crow = nf * 16 + lc;
        short8 bf = *(const short8*)&Ws[crow * 64 + ((gg ^ (crow & 7)) << 3)];
        acc[nf] = __builtin_amdgcn_mfma_f32_16x16x32_bf16(af, bf, acc[nf], 0, 0, 0);
      }
    }
    __syncthreads();
  }
  // bias + bounce C through LDS (bf16)
#pragma unroll
  for (int nf = 0; nf < 16; ++nf) {
    float bv = bias[nf * 16 + lc];
#pragma unroll
    for (int r = 0; r < 4; ++r)
      Ct[(w * 16 + (lg << 2) + r) * 264 + nf * 16 + lc] = f2bf(acc[nf][r] + bv);
  }
  __syncthreads();
  // LN epilogue: thread = (row i, col-quarter qq); Ct double-read
  int i = tid >> 2, qq = tid & 3;
  float s1 = 0.f, s2 = 0.f;
#pragma unroll
  for (int j2 = 0; j2 < 8; ++j2) {
    uint4 u = *(const uint4*)&Ct[i * 264 + qq * 64 + j2 * 8];
    u32 ua[4] = {u.x, u.y, u.z, u.w};
#pragma unroll
    for (int k = 0; k < 4; ++k) {
      float a = bflo(ua[k]), c = bfhi(ua[k]);
      s1 += a + c;
      s2 += a * a + c * c;
    }
  }
  s1 += __shfl_xor(s1, 1);
  s1 += __shfl_xor(s1, 2);
  s2 += __shfl_xor(s2, 1);
  s2 += __shfl_xor(s2, 2);
  float mean = s1 * (1.f / 256.f);
  float var = s2 * (1.f / 256.f) - mean * mean;
  float rs = rsqrtf(var + 1e-5f);
  int p = m0 + i;
  int b = p >> 14, hw = p & 16383;
  size_t rbase = (size_t)p * 256 + qq * 64;
#pragma unroll
  for (int j2 = 0; j2 < 8; ++j2) {
    uint4 cu = *(const uint4*)&Ct[i * 264 + qq * 64 + j2 * 8];
    u32 ca[4] = {cu.x, cu.y, cu.z, cu.w};
    uint4 u = *(const uint4*)(res + rbase + j2 * 8);
    u32 ua[4] = {u.x, u.y, u.z, u.w};
#pragma unroll
    for (int k = 0; k < 4; ++k) {
      int c = qq * 64 + j2 * 8 + 2 * k;
      float o0 = bflo(ua[k]) + (bflo(ca[k]) - mean) * rs * g[c] + bb[c];
      float o1 = bfhi(ua[k]) + (bfhi(ca[k]) - mean) * rs * g[c + 1] + bb[c + 1];
      outf[(size_t)(b * 256 + c) * HW + hw] = o0;
      outf[(size_t)(b * 256 + c + 1) * HW + hw] = o1;
    }
  }
}

// ---------------------------------------------------------------------------
extern "C" void kernel_launch(void* const* d_in, const int* in_sizes, int n_in,
                              void* d_out, int out_size, void* d_ws, size_t ws_size,
                              hipStream_t stream) {
  const float* x        = (const float*)d_in[0];
  const float* w_stem   = (const float*)d_in[1];
  const float* s_stem   = (const float*)d_in[2];
  const float* b_stem   = (const float*)d_in[3];
  const float* w_blk    = (const float*)d_in[4];
  const float* s_blk    = (const float*)d_in[5];
  const float* b_blk    = (const float*)d_in[6];
  const float* norm1_g  = (const float*)d_in[7];
  const float* norm1_b  = (const float*)d_in[8];
  const float* qkv_w    = (const float*)d_in[9];
  const float* qkv_b    = (const float*)d_in[10];
  const float* proj_w   = (const float*)d_in[11];
  const float* proj_b   = (const float*)d_in[12];
  const float* logit_sc = (const float*)d_in[13];
  const float* cpb_w1   = (const float*)d_in[14];
  const float* cpb_b1   = (const float*)d_in[15];
  const float* cpb_w2   = (const float*)d_in[16];
  const float* norm2_g  = (const float*)d_in[17];
  const float* norm2_b  = (const float*)d_in[18];
  const float* mlp_w1   = (const float*)d_in[19];
  const float* mlp_b1   = (const float*)d_in[20];
  const float* mlp_w2   = (const float*)d_in[21];
  const float* mlp_b2   = (const float*)d_in[22];
  float* out = (float*)d_out;
  float* ws = (float*)d_ws;
  (void)in_sizes; (void)n_in; (void)out_size; (void)ws_size;

  // ---- workspace regions (floats) ----
  float* R0 = ws;                  // 16,777,216
  float* R1 = ws + 16777216;       // 16,777,216
  float* R2 = ws + 33554432;       // 16,777,216
  float* TAIL = ws + 50331648;
  u16* WTC  = (u16*)TAIL;
  u16* WTS  = (u16*)(TAIL + 73728);
  u16* QWB  = (u16*)(TAIL + 81920);
  u16* PWB  = (u16*)(TAIL + 180224);
  u16* M1WB = (u16*)(TAIL + 212992);
  u16* M2WB = (u16*)(TAIL + 245760);
  float* BPRE = TAIL + 278528;
  float* BFT  = TAIL + 280576;

  // phase overlays (R13-verified lifetimes):
  u16* XT  = (u16*)R2;               // dead after stem gemm
  u16* EBF = (u16*)(R2 + 8388608);   // NHWC e; alive until ln1v
  u16* T1  = (u16*)R1;               // conv intermediates
  u16* T2  = (u16*)(R1 + 2097152);
  u16* AO  = (u16*)R0;               // attn out token-major
  u16* P   = (u16*)(R0 + 8388608);   // proj out token-major
  u16* SBF = (u16*)R0;               // S bf16 pixel-major (over dead AO)
  u16* Hb  = (u16*)R2;               // mlp hidden (over dead XT)

  // ---- param prep (one kernel) + CPB ----
  prep_kernel<<<2176, 256, 0, stream>>>(w_blk, s_blk, w_stem, s_stem, qkv_w,
                                        proj_w, mlp_w1, mlp_w2, WTC, WTS, QWB,
                                        PWB, M1WB, M2WB);
  cpb_mlp_kernel<<<225, 512, 0, stream>>>(cpb_w1, cpb_b1, cpb_w2, BPRE);
  cpb_expand_kernel<<<16, 256, 0, stream>>>(BPRE, BFT);

  // ---- input transpose + stem (1x1 conv = GEMM, SiLU) -> EBF ch 128..255 ----
  transpose_in_kernel<<<2048, 256, 0, stream>>>(x, XT);
  dim3 gs(2, 512);
  gemm_bf16_kernel<<<gs, 256, 0, stream>>>(XT, WTS, b_stem, EBF + 128, 128, 256, 2);

  // ---- ELAN 3x3 convs (bf16 MFMA implicit GEMM) ----
  dim3 cgrid(16, 16, 4);
  conv3x3_mfma_kernel<<<cgrid, 256, 0, stream>>>(EBF + 128, 256, T1, 64, WTC, b_blk);
  conv3x3_mfma_kernel<<<cgrid, 256, 0, stream>>>(T1, 64, EBF + 64, 256, WTC + 9 * 4096, b_blk + 64);
  conv3x3_mfma_kernel<<<cgrid, 256, 0, stream>>>(EBF + 64, 256, T2, 64, WTC + 18 * 4096, b_blk + 128);
  conv3x3_mfma_kernel<<<cgrid, 256, 0, stream>>>(T2, 64, EBF, 256, WTC + 27 * 4096, b_blk + 192);

  // ---- fused qkv + window attention v6 (1024 windows x 512 thr) ----
  attn_fused_kernel<<<1024, 512, 0, stream>>>(EBF, QWB, qkv_b, logit_sc, BFT, AO);

  // ---- proj + LN1 (proven pair), MLP1, fused mlp2+LN2+transpose ----
  dim3 g4(4, 512);
  gemm_bf16_kernel<<<g4, 256, 0, stream>>>(AO, PWB, proj_b, P, 256, 256, 0);
  ln1v_kernel<<<1024, 256, 0, stream>>>(P, EBF, SBF, norm1_g, norm1_b);
  gemm_bf16_kernel<<<g4, 256, 0, stream>>>(SBF, M1WB, mlp_b1, Hb, 256, 256, 1);
  gemm_ln2_kernel<<<1024, 256, 0, stream>>>(Hb, M2WB, mlp_b2, norm2_g, norm2_b,
                                            SBF, out);
}

// Round 18
// 430.059 us; speedup vs baseline: 1.1430x; 1.1430x over previous
//
#include <hip/hip_runtime.h>
#include <hip/hip_bf16.h>
#include <math.h>

// ---------------------------------------------------------------------------
// ELAN + SwinV2: bf16 MFMA convs + GEMMs; fused qkv+attention v6b (LDS 52KB
// for 3 blocks/CU, launch_bounds(512,4) to avoid spill); mlp2+LN2 fused.
// B=4, C_IN=128, H=W=128, DIM=256, WS=8, HEADS=8, HEAD_DIM=32.
// ---------------------------------------------------------------------------

#define HW 16384
typedef unsigned int u32;
typedef unsigned short u16;
typedef __attribute__((ext_vector_type(8))) short short8;   // bf16x8 MFMA frag
typedef __attribute__((ext_vector_type(4))) float floatx4;  // f32x4 acc frag

// compiler-only fence: blocks LDS load/store reordering (HW is in-order per wave)
#define MEMBAR() asm volatile("" ::: "memory")

__device__ __forceinline__ float silu_f(float y) { return y / (1.f + expf(-y)); }
__device__ __forceinline__ float bflo(u32 u) { return __uint_as_float(u << 16); }
__device__ __forceinline__ float bfhi(u32 u) { return __uint_as_float(u & 0xffff0000u); }
__device__ __forceinline__ float bf2f(u16 v) { return __uint_as_float((u32)v << 16); }
__device__ __forceinline__ u16 f2bf(float x) {
  u32 u = __float_as_uint(x);
  u += 0x7fffu + ((u >> 16) & 1u);
  return (u16)(u >> 16);
}
__device__ __forceinline__ u32 pack2(float a, float b) {
  return (u32)f2bf(a) | ((u32)f2bf(b) << 16);
}
__device__ __forceinline__ short8 mk8(u32 a, u32 b, u32 c, u32 d) {
  union { u32 u[4]; short8 s; } t;
  t.u[0] = a; t.u[1] = b; t.u[2] = c; t.u[3] = d;
  return t.s;
}
// both shfls executed by all lanes (uniform), then per-lane select
__device__ __forceinline__ u32 shfl_sel(u32 va, u32 vb, int s, bool sel) {
  u32 x = (u32)__shfl((int)va, s);
  u32 y = (u32)__shfl((int)vb, s);
  return sel ? y : x;
}

#define GLDS16(gp, lp)                                           \
  __builtin_amdgcn_global_load_lds(                              \
      (const __attribute__((address_space(1))) void*)(gp),       \
      (__attribute__((address_space(3))) void*)(lp), 16, 0, 0)

// ---------------- unified prep: conv/stem repack + qkv/proj/mlp casts -------
__global__ __launch_bounds__(256) void prep_kernel(
    const float* __restrict__ w_blk, const float* __restrict__ s_blk,
    const float* __restrict__ w_stem, const float* __restrict__ s_stem,
    const float* __restrict__ qkv_w, const float* __restrict__ proj_w,
    const float* __restrict__ mlp_w1, const float* __restrict__ mlp_w2,
    u16* __restrict__ wtc, u16* __restrict__ wts, u16* __restrict__ qwb,
    u16* __restrict__ pwb, u16* __restrict__ m1wb, u16* __restrict__ m2wb) {
  int idx = blockIdx.x * 256 + threadIdx.x;
  if (idx < 147456) {
    int c = idx & 63;
    int rest = idx >> 6;
    int oc = rest & 63;
    int ct = rest >> 6;
    int conv = ct / 9, t = ct % 9;
    float w = w_blk[((size_t)(conv * 64 + oc) * 64 + c) * 9 + t];
    wtc[idx] = f2bf(w * s_blk[conv * 64 + oc]);
  } else if (idx < 163840) {
    int j = idx - 147456;
    int c = j & 127, oc = j >> 7;
    wts[j] = f2bf(w_stem[(size_t)oc * 128 + c] * s_stem[oc]);
  } else if (idx < 360448) {
    int j = idx - 163840;
    qwb[j] = f2bf(qkv_w[j]);
  } else if (idx < 425984) {
    int j = idx - 360448;
    pwb[j] = f2bf(proj_w[j]);
  } else if (idx < 491520) {
    int j = idx - 425984;
    m1wb[j] = f2bf(mlp_w1[j]);
  } else if (idx < 557056) {
    int j = idx - 491520;
    m2wb[j] = f2bf(mlp_w2[j]);
  }
}

// ---------------- continuous position bias MLP -----------------------------
__global__ __launch_bounds__(512) void cpb_mlp_kernel(
    const float* __restrict__ w1, const float* __restrict__ b1,
    const float* __restrict__ w2, float* __restrict__ pre) {
  __shared__ float hb[512];
  int t = blockIdx.x, j = threadIdx.x;
  int i = t / 15, jj = t % 15;
  float c0 = (float)(i - 7) * (8.f / 7.f);
  float c1 = (float)(jj - 7) * (8.f / 7.f);
  float s0 = (c0 > 0.f) ? 1.f : ((c0 < 0.f) ? -1.f : 0.f);
  float s1 = (c1 > 0.f) ? 1.f : ((c1 < 0.f) ? -1.f : 0.f);
  float t0 = s0 * log2f(fabsf(c0) + 1.f) * (1.f / 3.f);
  float t1 = s1 * log2f(fabsf(c1) + 1.f) * (1.f / 3.f);
  float h = t0 * w1[j * 2] + t1 * w1[j * 2 + 1] + b1[j];
  hb[j] = fmaxf(h, 0.f);
  __syncthreads();
  if (j < 8) {
    float s = 0.f;
    for (int k = 0; k < 512; ++k) s += hb[k] * w2[j * 512 + k];
    pre[t * 8 + j] = s;
  }
}

// bias_t2[h][m>>1][n][m&1]: row-pair float2 layout (4096 floats/head)
__global__ __launch_bounds__(256) void cpb_expand_kernel(
    const float* __restrict__ pre, float* __restrict__ bias_t) {
  int idx = blockIdx.x * 256 + threadIdx.x;
  int m = idx >> 6, n = idx & 63;
  int di = (n >> 3) - (m >> 3) + 7;
  int dj = (n & 7) - (m & 7) + 7;
  int ti = di * 15 + dj;
#pragma unroll
  for (int h = 0; h < 8; ++h) {
    float v = pre[ti * 8 + h];
    bias_t[h * 4096 + (((m >> 1) * 64 + n) << 1) + (m & 1)] =
        16.f / (1.f + expf(-v));
  }
}

// ---------------- x NCHW fp32 -> XT NHWC bf16 -------------------------------
__global__ __launch_bounds__(256) void transpose_in_kernel(
    const float* __restrict__ x, u16* __restrict__ xt) {
  __shared__ float tl[64][65];
  int bid = blockIdx.x;
  int b = bid >> 9;
  int r = bid & 511;
  int cs = r >> 8, hws = r & 255;
  int c0 = cs << 6, hw0 = hws << 6;
  int tid = threadIdx.x;
  for (int e = tid; e < 4096; e += 256) {
    int c = e >> 6, p = e & 63;
    tl[c][p] = x[(size_t)(b * 128 + c0 + c) * HW + hw0 + p];
  }
  __syncthreads();
  for (int e = tid; e < 4096; e += 256) {
    int p = e >> 6, c = e & 63;
    xt[(size_t)(b * HW + hw0 + p) * 128 + c0 + c] = f2bf(tl[c][p]);
  }
}

// ---------------- bf16 MFMA GEMM: C[.,col]=act(A[M,K] @ W[N,K]^T + b) -------
__global__ __launch_bounds__(256, 4) void gemm_bf16_kernel(
    const u16* __restrict__ A, const u16* __restrict__ W,
    const float* __restrict__ bias, u16* __restrict__ C, int K, int ldc,
    int act) {
  __shared__ u16 As[128 * 64];
  __shared__ u16 Ws[64 * 64];
  int tid = threadIdx.x;
  int wv = tid >> 6, lane = tid & 63;
  int m0 = blockIdx.y * 128, n0 = blockIdx.x * 64;
  floatx4 zz = {0.f, 0.f, 0.f, 0.f};
  floatx4 acc[2][4];
#pragma unroll
  for (int i = 0; i < 2; ++i)
#pragma unroll
    for (int j = 0; j < 4; ++j) acc[i][j] = zz;
  int lr = lane >> 3, ls = lane & 7;
  for (int k0 = 0; k0 < K; k0 += 64) {
#pragma unroll
    for (int i = 0; i < 4; ++i) {
      int ci = wv * 4 + i;
      int r = ci * 8 + lr;
      int cc = ls ^ (r & 7);
      GLDS16(A + (size_t)(m0 + r) * K + k0 + cc * 8, As + ci * 512);
    }
#pragma unroll
    for (int i = 0; i < 2; ++i) {
      int ci = wv * 2 + i;
      int r = ci * 8 + lr;
      int cc = ls ^ (r & 7);
      GLDS16(W + (size_t)(n0 + r) * K + k0 + cc * 8, Ws + ci * 512);
    }
    __syncthreads();
#pragma unroll
    for (int kk = 0; kk < 2; ++kk) {
      int g = kk * 4 + (lane >> 4);
      short8 a0, a1, b0, b1, b2, b3;
      {
        int row = wv * 32 + (lane & 15);
        a0 = *(const short8*)&As[row * 64 + (g ^ (row & 7)) * 8];
        int row2 = row + 16;
        a1 = *(const short8*)&As[row2 * 64 + (g ^ (row2 & 7)) * 8];
      }
      {
        int col = lane & 15;
        b0 = *(const short8*)&Ws[col * 64 + (g ^ (col & 7)) * 8];
        int c1 = col + 16;
        b1 = *(const short8*)&Ws[c1 * 64 + (g ^ (c1 & 7)) * 8];
        int c2 = col + 32;
        b2 = *(const short8*)&Ws[c2 * 64 + (g ^ (c2 & 7)) * 8];
        int c3 = col + 48;
        b3 = *(const short8*)&Ws[c3 * 64 + (g ^ (c3 & 7)) * 8];
      }
      acc[0][0] = __builtin_amdgcn_mfma_f32_16x16x32_bf16(a0, b0, acc[0][0], 0, 0, 0);
      acc[0][1] = __builtin_amdgcn_mfma_f32_16x16x32_bf16(a0, b1, acc[0][1], 0, 0, 0);
      acc[0][2] = __builtin_amdgcn_mfma_f32_16x16x32_bf16(a0, b2, acc[0][2], 0, 0, 0);
      acc[0][3] = __builtin_amdgcn_mfma_f32_16x16x32_bf16(a0, b3, acc[0][3], 0, 0, 0);
      acc[1][0] = __builtin_amdgcn_mfma_f32_16x16x32_bf16(a1, b0, acc[1][0], 0, 0, 0);
      acc[1][1] = __builtin_amdgcn_mfma_f32_16x16x32_bf16(a1, b1, acc[1][1], 0, 0, 0);
      acc[1][2] = __builtin_amdgcn_mfma_f32_16x16x32_bf16(a1, b2, acc[1][2], 0, 0, 0);
      acc[1][3] = __builtin_amdgcn_mfma_f32_16x16x32_bf16(a1, b3, acc[1][3], 0, 0, 0);
    }
    __syncthreads();
  }
  int rbase = wv * 32 + ((lane >> 4) << 2);
  int cb = lane & 15;
#pragma unroll
  for (int mi = 0; mi < 2; ++mi) {
#pragma unroll
    for (int nj = 0; nj < 4; ++nj) {
      int col = n0 + nj * 16 + cb;
      float bv = bias[col];
#pragma unroll
      for (int r = 0; r < 4; ++r) {
        int row = m0 + rbase + mi * 16 + r;
        float v = acc[mi][nj][r] + bv;
        if (act == 1) v = 0.5f * v * (1.f + erff(v * 0.70710678118654752f));
        else if (act == 2) v = silu_f(v);
        C[(size_t)row * ldc + col] = f2bf(v);
      }
    }
  }
}

// ---------------- 3x3 conv 64->64 pad1 SiLU, NHWC bf16, implicit MFMA GEMM --
__global__ __launch_bounds__(256) void conv3x3_mfma_kernel(
    const u16* __restrict__ in, int istr, u16* __restrict__ outp, int ostr,
    const u16* __restrict__ wt, const float* __restrict__ bias) {
  __shared__ u16 tile[6400];
  int tid = threadIdx.x;
  int wv = tid >> 6, lane = tid & 63;
  int bx = blockIdx.x, by = blockIdx.y, b = blockIdx.z;
  int h0 = by * 8, w0 = bx * 8;
#pragma unroll
  for (int rr = 0; rr < 4; ++rr) {
    int slot = rr * 256 + tid;
    int p = slot >> 3, ch = slot & 7;
    if (p < 100) {
      int hr = p / 10, hc = p % 10;
      int gh = h0 + hr - 1, gw = w0 + hc - 1;
      bool ok = (gh >= 0) && (gh < 128) && (gw >= 0) && (gw < 128);
      uint4 v = {0u, 0u, 0u, 0u};
      if (ok) {
        size_t pix = (size_t)((b * 128 + gh) * 128 + gw);
        v = *(const uint4*)(in + pix * istr + ch * 8);
      }
      *(uint4*)(tile + p * 64 + ((ch ^ (p & 7)) << 3)) = v;
    }
  }
  __syncthreads();
  int pl = lane & 15;
  int g = lane >> 4;
  int prow = 2 * wv + (pl >> 3), pcol = pl & 7;
  floatx4 zz = {0.f, 0.f, 0.f, 0.f};
  floatx4 acc[4] = {zz, zz, zz, zz};
#pragma unroll
  for (int t = 0; t < 9; ++t) {
    int dy = t / 3, dx = t % 3;
    int hp = (prow + dy) * 10 + (pcol + dx);
    short8 bf0 = *(const short8*)&tile[hp * 64 + (((0 * 4 + g) ^ (hp & 7)) << 3)];
    short8 bf1 = *(const short8*)&tile[hp * 64 + (((1 * 4 + g) ^ (hp & 7)) << 3)];
    const u16* wtap = wt + t * 4096;
#pragma unroll
    for (int nf = 0; nf < 4; ++nf) {
      short8 a0 = *(const short8*)&wtap[(nf * 16 + pl) * 64 + g * 8];
      short8 a1 = *(const short8*)&wtap[(nf * 16 + pl) * 64 + 32 + g * 8];
      acc[nf] = __builtin_amdgcn_mfma_f32_16x16x32_bf16(a0, bf0, acc[nf], 0, 0, 0);
      acc[nf] = __builtin_amdgcn_mfma_f32_16x16x32_bf16(a1, bf1, acc[nf], 0, 0, 0);
    }
  }
  size_t pix = (size_t)((b * 128 + h0 + prow) * 128 + w0 + pcol);
#pragma unroll
  for (int nf = 0; nf < 4; ++nf) {
    float o0 = silu_f(acc[nf][0] + bias[nf * 16 + g * 4 + 0]);
    float o1 = silu_f(acc[nf][1] + bias[nf * 16 + g * 4 + 1]);
    float o2 = silu_f(acc[nf][2] + bias[nf * 16 + g * 4 + 2]);
    float o3 = silu_f(acc[nf][3] + bias[nf * 16 + g * 4 + 3]);
    uint2 w2;
    w2.x = pack2(o0, o1);
    w2.y = pack2(o2, o3);
    *(uint2*)(outp + pix * ostr + nf * 16 + g * 4) = w2;
  }
}

// ---------------- fused qkv-GEMM + window attention v6b ---------------------
// block = 1 window x 8 heads (512 thr, wave = head). E staged once (32KB).
// Per-wave 2.5KB scratch: K/Q transposed in two 32-row rounds. Ol bounce
// overlays dead Elds after barrier #2. LDS 52KB; launch_bounds(512,4).
__device__ __forceinline__ void qkv_mm(const u16* Elds, const u16* qwb,
                                       int moff, int h, int lc, int lg,
                                       floatx4 acc[4][2]) {
  floatx4 zz = {0.f, 0.f, 0.f, 0.f};
#pragma unroll
  for (int mf = 0; mf < 4; ++mf) {
    acc[mf][0] = zz;
    acc[mf][1] = zz;
  }
#pragma unroll
  for (int ks = 0; ks < 8; ++ks) {
    int ch = ks >> 1, g = ((ks & 1) << 2) + lg;
    short8 af[4];
#pragma unroll
    for (int mf = 0; mf < 4; ++mf) {
      int tk = mf * 16 + lc;
      af[mf] = *(const short8*)&Elds[(ch * 64 + tk) * 64 + ((g ^ (tk & 7)) << 3)];
    }
#pragma unroll
    for (int nf = 0; nf < 2; ++nf) {
      short8 bf = *(const short8*)(qwb +
          (size_t)(moff + h * 32 + nf * 16 + lc) * 256 + ks * 32 + lg * 8);
#pragma unroll
      for (int mf = 0; mf < 4; ++mf)
        acc[mf][nf] =
            __builtin_amdgcn_mfma_f32_16x16x32_bf16(af[mf], bf, acc[mf][nf], 0, 0, 0);
    }
  }
}

__global__ __launch_bounds__(512, 4) void attn_fused_kernel(
    const u16* __restrict__ ebf, const u16* __restrict__ qwb,
    const float* __restrict__ qkv_b, const float* __restrict__ logit_scale,
    const float* __restrict__ bias_t, u16* __restrict__ ao) {
  __shared__ __align__(16) char lds[53248];
  int tid = threadIdx.x;
  int w = tid >> 6, l = tid & 63;
  int wid = blockIdx.x;
  int h = __builtin_amdgcn_readfirstlane(w);
  u16* Elds = (u16*)lds;              // [4 chunks][64 rows][64] swizzled (32KB)
  char* Sc = lds + 32768 + w * 2560;  // per-wave scratch [32 rows][80B]

  int b = wid >> 8, wh = (wid >> 4) & 15, ww = wid & 15;
  int pixbase = (b << 14) + wh * 1024 + ww * 8;
  {  // stage E window once: wave w stages half of chunk w>>1
    int lr = l >> 3, ls = l & 7;
    int ch = w >> 1;
#pragma unroll
    for (int j = 0; j < 4; ++j) {
      int jj = ((w & 1) << 2) + j;
      int pix = pixbase + jj * 128 + lr;
      GLDS16(ebf + (size_t)pix * 256 + ch * 64 + ((ls ^ lr) << 3),
             Elds + (ch * 8 + jj) * 512);
    }
  }
  __syncthreads();  // barrier #1: E staged

  int lc = l & 15, lg = l >> 4;
  float scale = __expf(fminf(logit_scale[h], 4.6051701860f));
  floatx4 macc[4][2];
  short8 kf[4], qf[4];

  // ---- K: project, normalize; transpose via 32-row scratch, 2 rounds ----
  qkv_mm(Elds, qwb, 256, h, lc, lg, macc);
#pragma unroll
  for (int half = 0; half < 2; ++half) {
#pragma unroll
    for (int mf2 = 0; mf2 < 2; ++mf2) {
      int mf = half * 2 + mf2;
#pragma unroll
      for (int r = 0; r < 4; ++r) {
        float v0 = macc[mf][0][r], v1 = macc[mf][1][r];
        float ss = v0 * v0 + v1 * v1;
        ss += __shfl_xor(ss, 1);
        ss += __shfl_xor(ss, 2);
        ss += __shfl_xor(ss, 4);
        ss += __shfl_xor(ss, 8);
        float rk = 1.f / fmaxf(sqrtf(ss), 1e-12f);
        int tk = mf2 * 16 + (lg << 2) + r;
        *(u16*)(Sc + tk * 80 + lc * 2) = f2bf(v0 * rk);
        *(u16*)(Sc + tk * 80 + (16 + lc) * 2) = f2bf(v1 * rk);
      }
    }
    MEMBAR();
#pragma unroll
    for (int i = 0; i < 2; ++i)
      kf[half * 2 + i] = *(const short8*)(Sc + (i * 16 + lc) * 80 + (lg << 4));
    MEMBAR();
  }

  // ---- Q: project+bias, normalize*scale; 2-round transpose -> qf ----
  qkv_mm(Elds, qwb, 0, h, lc, lg, macc);
  {
    float qb0 = qkv_b[h * 32 + lc], qb1 = qkv_b[h * 32 + 16 + lc];
#pragma unroll
    for (int half = 0; half < 2; ++half) {
#pragma unroll
      for (int mf2 = 0; mf2 < 2; ++mf2) {
        int mf = half * 2 + mf2;
#pragma unroll
        for (int r = 0; r < 4; ++r) {
          float v0 = macc[mf][0][r] + qb0, v1 = macc[mf][1][r] + qb1;
          float ss = v0 * v0 + v1 * v1;
          ss += __shfl_xor(ss, 1);
          ss += __shfl_xor(ss, 2);
          ss += __shfl_xor(ss, 4);
          ss += __shfl_xor(ss, 8);
          float rq = scale / fmaxf(sqrtf(ss), 1e-12f);
          int tk = mf2 * 16 + (lg << 2) + r;
          *(u16*)(Sc + tk * 80 + lc * 2) = f2bf(v0 * rq);
          *(u16*)(Sc + tk * 80 + (16 + lc) * 2) = f2bf(v1 * rq);
        }
      }
      MEMBAR();
#pragma unroll
      for (int i = 0; i < 2; ++i)
        qf[half * 2 + i] = *(const short8*)(Sc + (i * 16 + lc) * 80 + (lg << 4));
      MEMBAR();
    }
  }

  // ---- V: project + bias, pack bf16 pairs in regs ----
  u32 v01[4][2], v23[4][2];
  qkv_mm(Elds, qwb, 512, h, lc, lg, macc);
  {
    float vb0 = qkv_b[512 + h * 32 + lc], vb1 = qkv_b[512 + h * 32 + 16 + lc];
#pragma unroll
    for (int mf = 0; mf < 4; ++mf) {
      v01[mf][0] = pack2(macc[mf][0][0] + vb0, macc[mf][0][1] + vb0);
      v23[mf][0] = pack2(macc[mf][0][2] + vb0, macc[mf][0][3] + vb0);
      v01[mf][1] = pack2(macc[mf][1][0] + vb1, macc[mf][1][1] + vb1);
      v23[mf][1] = pack2(macc[mf][1][2] + vb1, macc[mf][1][3] + vb1);
    }
  }

  // ---- S^T = Kn @ Qs^T ----
  floatx4 zz = {0.f, 0.f, 0.f, 0.f};
  floatx4 S[4][4];
#pragma unroll
  for (int mi = 0; mi < 4; ++mi)
#pragma unroll
    for (int ni = 0; ni < 4; ++ni)
      S[mi][ni] = __builtin_amdgcn_mfma_f32_16x16x32_bf16(kf[mi], qf[ni], zz, 0, 0, 0);

  // softmax: bias loaded as row-pair float2 (identical values, half the loads)
  const float* bh = bias_t + h * 4096;
  float den[4] = {0.f, 0.f, 0.f, 0.f};
#pragma unroll
  for (int mi = 0; mi < 4; ++mi) {
#pragma unroll
    for (int r2 = 0; r2 < 2; ++r2) {
      int m2 = mi * 8 + (lg << 1) + r2;
#pragma unroll
      for (int ni = 0; ni < 4; ++ni) {
        int nn = ni * 16 + lc;
        float2 bp = *(const float2*)(bh + ((m2 * 64 + nn) << 1));
        float e0 = __expf(S[mi][ni][2 * r2] + bp.x);
        float e1 = __expf(S[mi][ni][2 * r2 + 1] + bp.y);
        S[mi][ni][2 * r2] = e0;
        S[mi][ni][2 * r2 + 1] = e1;
        den[ni] += e0 + e1;
      }
    }
  }
#pragma unroll
  for (int ni = 0; ni < 4; ++ni) {
    den[ni] += __shfl_xor(den[ni], 16);
    den[ni] += __shfl_xor(den[ni], 32);
    den[ni] = 1.f / den[ni];
  }
  // P packs (inv folded): p01/p23[mi][ni] hold rows m=mi*16+lg*4+{0,1}/{2,3}
  u32 p01[4][4], p23[4][4];
#pragma unroll
  for (int mi = 0; mi < 4; ++mi)
#pragma unroll
    for (int ni = 0; ni < 4; ++ni) {
      p01[mi][ni] = pack2(S[mi][ni][0] * den[ni], S[mi][ni][1] * den[ni]);
      p23[mi][ni] = pack2(S[mi][ni][2] * den[ni], S[mi][ni][3] * den[ni]);
    }

  // ---- lg-quarter exchange: build V frags and P frags in-register ----
  int s1 = ((lg & 1) << 5) + lc;  // source lane (lg_s=(lg&1)*2, lc)
  int s2 = s1 + 16;
  bool hi = lg >= 2;              // selects odd mf/mi candidate
  short8 vf[2][2];
#pragma unroll
  for (int ks = 0; ks < 2; ++ks)
#pragma unroll
    for (int db = 0; db < 2; ++db) {
      u32 w0 = shfl_sel(v01[ks * 2][db], v01[ks * 2 + 1][db], s1, hi);
      u32 w1 = shfl_sel(v23[ks * 2][db], v23[ks * 2 + 1][db], s1, hi);
      u32 w2 = shfl_sel(v01[ks * 2][db], v01[ks * 2 + 1][db], s2, hi);
      u32 w3 = shfl_sel(v23[ks * 2][db], v23[ks * 2 + 1][db], s2, hi);
      vf[ks][db] = mk8(w0, w1, w2, w3);
    }
  floatx4 O[4][2];
#pragma unroll
  for (int nb = 0; nb < 4; ++nb) {
    u32 a0 = shfl_sel(p01[0][nb], p01[1][nb], s1, hi);
    u32 a1 = shfl_sel(p23[0][nb], p23[1][nb], s1, hi);
    u32 a2 = shfl_sel(p01[0][nb], p01[1][nb], s2, hi);
    u32 a3 = shfl_sel(p23[0][nb], p23[1][nb], s2, hi);
    short8 pf0 = mk8(a0, a1, a2, a3);
    u32 b0 = shfl_sel(p01[2][nb], p01[3][nb], s1, hi);
    u32 b1 = shfl_sel(p23[2][nb], p23[3][nb], s1, hi);
    u32 b2 = shfl_sel(p01[2][nb], p01[3][nb], s2, hi);
    u32 b3 = shfl_sel(p23[2][nb], p23[3][nb], s2, hi);
    short8 pf1 = mk8(b0, b1, b2, b3);
    floatx4 o0 = __builtin_amdgcn_mfma_f32_16x16x32_bf16(pf0, vf[0][0], zz, 0, 0, 0);
    o0 = __builtin_amdgcn_mfma_f32_16x16x32_bf16(pf1, vf[1][0], o0, 0, 0, 0);
    floatx4 o1 = __builtin_amdgcn_mfma_f32_16x16x32_bf16(pf0, vf[0][1], zz, 0, 0, 0);
    o1 = __builtin_amdgcn_mfma_f32_16x16x32_bf16(pf1, vf[1][1], o1, 0, 0, 0);
    O[nb][0] = o0;
    O[nb][1] = o1;
  }

  // ---- barrier #2: all E reads done; Elds becomes per-wave Ol bounce ----
  __syncthreads();
  char* Ol = lds + (w << 12);  // 4KB/wave, rows of 64B (no pad)
#pragma unroll
  for (int nb = 0; nb < 4; ++nb)
#pragma unroll
    for (int r = 0; r < 4; ++r) {
      int n = nb * 16 + (lg << 2) + r;
      *(u16*)(Ol + n * 64 + lc * 2) = f2bf(O[nb][0][r]);
      *(u16*)(Ol + n * 64 + (16 + lc) * 2) = f2bf(O[nb][1][r]);
    }
  MEMBAR();
  u32 ov[16];
#pragma unroll
  for (int j = 0; j < 16; ++j) ov[j] = *(const u32*)(Ol + l * 64 + j * 4);
  uint4* op = (uint4*)(ao + (size_t)(wid * 64 + l) * 256 + h * 32);
#pragma unroll
  for (int q4 = 0; q4 < 4; ++q4) {
    uint4 v;
    v.x = ov[q4 * 4 + 0];
    v.y = ov[q4 * 4 + 1];
    v.z = ov[q4 * 4 + 2];
    v.w = ov[q4 * 4 + 3];
    op[q4] = v;
  }
}

// ---------------- LN1: SBF = bf16( EBF + LN(P) ), vectorized (R4) -----------
__global__ __launch_bounds__(256) void ln1v_kernel(
    const u16* __restrict__ pin, const u16* __restrict__ ebf,
    u16* __restrict__ sbf, const float* __restrict__ g,
    const float* __restrict__ bb) {
  int tid = threadIdx.x;
  int bid = blockIdx.x;  // 1024 = b(4) x 256 groups of 64 pixels
  int b = bid >> 8, hw0 = (bid & 255) << 6;
  int i = tid >> 2, qq = tid & 3;
  int hw = hw0 + i;
  int him = hw >> 7, wim = hw & 127;
  int wid = b * 256 + (him >> 3) * 16 + (wim >> 3);
  int t = wid * 64 + (him & 7) * 8 + (wim & 7);
  size_t pbase = (size_t)t * 256 + qq * 64;
  size_t ebase = ((size_t)(b * HW + hw)) * 256 + qq * 64;
  float v[64];
  float s1 = 0.f, s2 = 0.f;
#pragma unroll
  for (int j = 0; j < 8; ++j) {
    uint4 u = *(const uint4*)(pin + pbase + j * 8);
    u32 ua[4] = {u.x, u.y, u.z, u.w};
#pragma unroll
    for (int k = 0; k < 4; ++k) {
      float a = bflo(ua[k]), c = bfhi(ua[k]);
      v[j * 8 + 2 * k] = a;
      v[j * 8 + 2 * k + 1] = c;
      s1 += a + c;
      s2 += a * a + c * c;
    }
  }
  s1 += __shfl_xor(s1, 1);
  s1 += __shfl_xor(s1, 2);
  s2 += __shfl_xor(s2, 1);
  s2 += __shfl_xor(s2, 2);
  float mean = s1 * (1.f / 256.f);
  float var = s2 * (1.f / 256.f) - mean * mean;
  float rs = rsqrtf(var + 1e-5f);
#pragma unroll
  for (int j = 0; j < 8; ++j) {
    uint4 u = *(const uint4*)(ebf + ebase + j * 8);
    u32 ua[4] = {u.x, u.y, u.z, u.w};
    uint4 o;
    u32 ow[4];
#pragma unroll
    for (int k = 0; k < 4; ++k) {
      int c = qq * 64 + j * 8 + 2 * k;
      float o0 = bflo(ua[k]) + (v[j * 8 + 2 * k] - mean) * rs * g[c] + bb[c];
      float o1 = bfhi(ua[k]) + (v[j * 8 + 2 * k + 1] - mean) * rs * g[c + 1] + bb[c + 1];
      ow[k] = pack2(o0, o1);
    }
    o.x = ow[0]; o.y = ow[1]; o.z = ow[2]; o.w = ow[3];
    *(uint4*)(sbf + ebase + j * 8) = o;
  }
}

// ---------------- fused mlp2-GEMM (64x256,K=256) + LN2 + residual + NCHW ----
// rows = pixels (no remap). A=Hb, res=SBF, out = NCHW fp32 final output.
__global__ __launch_bounds__(256, 4) void gemm_ln2_kernel(
    const u16* __restrict__ A, const u16* __restrict__ W,
    const float* __restrict__ bias, const float* __restrict__ g,
    const float* __restrict__ bb, const u16* __restrict__ res,
    float* __restrict__ outf) {
  __shared__ __align__(16) char lds[40960];
  u16* As = (u16*)lds;            // [64][64] per k-chunk
  u16* Ws = (u16*)(lds + 8192);   // [256][64]
  u16* Ct = (u16*)lds;            // overlay [64][264]
  int tid = threadIdx.x;
  int w = tid >> 6, l = tid & 63;
  int lr = l >> 3, ls = l & 7;
  int lc = l & 15, lg = l >> 4;
  int m0 = blockIdx.x << 6;
  floatx4 zz = {0.f, 0.f, 0.f, 0.f};
  floatx4 acc[16];
#pragma unroll
  for (int i = 0; i < 16; ++i) acc[i] = zz;
  for (int k0 = 0; k0 < 256; k0 += 64) {
#pragma unroll
    for (int j = 0; j < 2; ++j) {
      int ci = w * 2 + j;
      int r = ci * 8 + lr;
      GLDS16(A + (size_t)(m0 + r) * 256 + k0 + ((ls ^ (r & 7)) << 3),
             As + ci * 512);
    }
#pragma unroll
    for (int j = 0; j < 8; ++j) {
      int ci = w * 8 + j;
      int r = ci * 8 + lr;
      GLDS16(W + (size_t)r * 256 + k0 + ((ls ^ (r & 7)) << 3), Ws + ci * 512);
    }
    __syncthreads();
#pragma unroll
    for (int kk = 0; kk < 2; ++kk) {
      int gg = (kk << 2) + lg;
      int arow = w * 16 + lc;
      short8 af = *(const short8*)&As[arow * 64 + ((gg ^ (arow & 7)) << 3)];
#pragma unroll
      for (int nf = 0; nf < 16; ++nf) {
        int crow = nf * 16 + lc;
        short8 bf = *(const short8*)&Ws[crow * 64 + ((gg ^ (crow & 7)) << 3)];
        acc[nf] = __builtin_amdgcn_mfma_f32_16x16x32_bf16(af, bf, acc[nf], 0, 0, 0);
      }
    }
    __syncthreads();
  }
  // bias + bounce C through LDS (bf16)
#pragma unroll
  for (int nf = 0; nf < 16; ++nf) {
    float bv = bias[nf * 16 + lc];
#pragma unroll
    for (int r = 0; r < 4; ++r)
      Ct[(w * 16 + (lg << 2) + r) * 264 + nf * 16 + lc] = f2bf(acc[nf][r] + bv);
  }
  __syncthreads();
  // LN epilogue: thread = (row i, col-quarter qq); Ct double-read
  int i = tid >> 2, qq = tid & 3;
  float s1 = 0.f, s2 = 0.f;
#pragma unroll
  for (int j2 = 0; j2 < 8; ++j2) {
    uint4 u = *(const uint4*)&Ct[i * 264 + qq * 64 + j2 * 8];
    u32 ua[4] = {u.x, u.y, u.z, u.w};
#pragma unroll
    for (int k = 0; k < 4; ++k) {
      float a = bflo(ua[k]), c = bfhi(ua[k]);
      s1 += a + c;
      s2 += a * a + c * c;
    }
  }
  s1 += __shfl_xor(s1, 1);
  s1 += __shfl_xor(s1, 2);
  s2 += __shfl_xor(s2, 1);
  s2 += __shfl_xor(s2, 2);
  float mean = s1 * (1.f / 256.f);
  float var = s2 * (1.f / 256.f) - mean * mean;
  float rs = rsqrtf(var + 1e-5f);
  int p = m0 + i;
  int b = p >> 14, hw = p & 16383;
  size_t rbase = (size_t)p * 256 + qq * 64;
#pragma unroll
  for (int j2 = 0; j2 < 8; ++j2) {
    uint4 cu = *(const uint4*)&Ct[i * 264 + qq * 64 + j2 * 8];
    u32 ca[4] = {cu.x, cu.y, cu.z, cu.w};
    uint4 u = *(const uint4*)(res + rbase + j2 * 8);
    u32 ua[4] = {u.x, u.y, u.z, u.w};
#pragma unroll
    for (int k = 0; k < 4; ++k) {
      int c = qq * 64 + j2 * 8 + 2 * k;
      float o0 = bflo(ua[k]) + (bflo(ca[k]) - mean) * rs * g[c] + bb[c];
      float o1 = bfhi(ua[k]) + (bfhi(ca[k]) - mean) * rs * g[c + 1] + bb[c + 1];
      outf[(size_t)(b * 256 + c) * HW + hw] = o0;
      outf[(size_t)(b * 256 + c + 1) * HW + hw] = o1;
    }
  }
}

// ---------------------------------------------------------------------------
extern "C" void kernel_launch(void* const* d_in, const int* in_sizes, int n_in,
                              void* d_out, int out_size, void* d_ws, size_t ws_size,
                              hipStream_t stream) {
  const float* x        = (const float*)d_in[0];
  const float* w_stem   = (const float*)d_in[1];
  const float* s_stem   = (const float*)d_in[2];
  const float* b_stem   = (const float*)d_in[3];
  const float* w_blk    = (const float*)d_in[4];
  const float* s_blk    = (const float*)d_in[5];
  const float* b_blk    = (const float*)d_in[6];
  const float* norm1_g  = (const float*)d_in[7];
  const float* norm1_b  = (const float*)d_in[8];
  const float* qkv_w    = (const float*)d_in[9];
  const float* qkv_b    = (const float*)d_in[10];
  const float* proj_w   = (const float*)d_in[11];
  const float* proj_b   = (const float*)d_in[12];
  const float* logit_sc = (const float*)d_in[13];
  const float* cpb_w1   = (const float*)d_in[14];
  const float* cpb_b1   = (const float*)d_in[15];
  const float* cpb_w2   = (const float*)d_in[16];
  const float* norm2_g  = (const float*)d_in[17];
  const float* norm2_b  = (const float*)d_in[18];
  const float* mlp_w1   = (const float*)d_in[19];
  const float* mlp_b1   = (const float*)d_in[20];
  const float* mlp_w2   = (const float*)d_in[21];
  const float* mlp_b2   = (const float*)d_in[22];
  float* out = (float*)d_out;
  float* ws = (float*)d_ws;
  (void)in_sizes; (void)n_in; (void)out_size; (void)ws_size;

  // ---- workspace regions (floats) ----
  float* R0 = ws;                  // 16,777,216
  float* R1 = ws + 16777216;       // 16,777,216
  float* R2 = ws + 33554432;       // 16,777,216
  float* TAIL = ws + 50331648;
  u16* WTC  = (u16*)TAIL;
  u16* WTS  = (u16*)(TAIL + 73728);
  u16* QWB  = (u16*)(TAIL + 81920);
  u16* PWB  = (u16*)(TAIL + 180224);
  u16* M1WB = (u16*)(TAIL + 212992);
  u16* M2WB = (u16*)(TAIL + 245760);
  float* BPRE = TAIL + 278528;
  float* BFT  = TAIL + 280576;

  // phase overlays (R13-verified lifetimes):
  u16* XT  = (u16*)R2;               // dead after stem gemm
  u16* EBF = (u16*)(R2 + 8388608);   // NHWC e; alive until ln1v
  u16* T1  = (u16*)R1;               // conv intermediates
  u16* T2  = (u16*)(R1 + 2097152);
  u16* AO  = (u16*)R0;               // attn out token-major
  u16* P   = (u16*)(R0 + 8388608);   // proj out token-major
  u16* SBF = (u16*)R0;               // S bf16 pixel-major (over dead AO)
  u16* Hb  = (u16*)R2;               // mlp hidden (over dead XT)

  // ---- param prep (one kernel) + CPB ----
  prep_kernel<<<2176, 256, 0, stream>>>(w_blk, s_blk, w_stem, s_stem, qkv_w,
                                        proj_w, mlp_w1, mlp_w2, WTC, WTS, QWB,
                                        PWB, M1WB, M2WB);
  cpb_mlp_kernel<<<225, 512, 0, stream>>>(cpb_w1, cpb_b1, cpb_w2, BPRE);
  cpb_expand_kernel<<<16, 256, 0, stream>>>(BPRE, BFT);

  // ---- input transpose + stem (1x1 conv = GEMM, SiLU) -> EBF ch 128..255 ----
  transpose_in_kernel<<<2048, 256, 0, stream>>>(x, XT);
  dim3 gs(2, 512);
  gemm_bf16_kernel<<<gs, 256, 0, stream>>>(XT, WTS, b_stem, EBF + 128, 128, 256, 2);

  // ---- ELAN 3x3 convs (bf16 MFMA implicit GEMM) ----
  dim3 cgrid(16, 16, 4);
  conv3x3_mfma_kernel<<<cgrid, 256, 0, stream>>>(EBF + 128, 256, T1, 64, WTC, b_blk);
  conv3x3_mfma_kernel<<<cgrid, 256, 0, stream>>>(T1, 64, EBF + 64, 256, WTC + 9 * 4096, b_blk + 64);
  conv3x3_mfma_kernel<<<cgrid, 256, 0, stream>>>(EBF + 64, 256, T2, 64, WTC + 18 * 4096, b_blk + 128);
  conv3x3_mfma_kernel<<<cgrid, 256, 0, stream>>>(T2, 64, EBF, 256, WTC + 27 * 4096, b_blk + 192);

  // ---- fused qkv + window attention v6b (1024 windows x 512 thr) ----
  attn_fused_kernel<<<1024, 512, 0, stream>>>(EBF, QWB, qkv_b, logit_sc, BFT, AO);

  // ---- proj + LN1 (proven pair), MLP1, fused mlp2+LN2+transpose ----
  dim3 g4(4, 512);
  gemm_bf16_kernel<<<g4, 256, 0, stream>>>(AO, PWB, proj_b, P, 256, 256, 0);
  ln1v_kernel<<<1024, 256, 0, stream>>>(P, EBF, SBF, norm1_g, norm1_b);
  gemm_bf16_kernel<<<g4, 256, 0, stream>>>(SBF, M1WB, mlp_b1, Hb, 256, 256, 1);
  gemm_ln2_kernel<<<1024, 256, 0, stream>>>(Hb, M2WB, mlp_b2, norm2_g, norm2_b,
                                            SBF, out);
}

// Round 19
// 409.769 us; speedup vs baseline: 1.1996x; 1.0495x over previous
//
#include <hip/hip_runtime.h>
#include <hip/hip_bf16.h>
#include <math.h>

// ---------------------------------------------------------------------------
// ELAN + SwinV2: bf16 MFMA convs + GEMMs; fused qkv+attention v4; mlp2+LN2
// fused (R13/R16-proven configuration, final).
// B=4, C_IN=128, H=W=128, DIM=256, WS=8, HEADS=8, HEAD_DIM=32.
// ---------------------------------------------------------------------------

#define HW 16384
typedef unsigned int u32;
typedef unsigned short u16;
typedef __attribute__((ext_vector_type(8))) short short8;   // bf16x8 MFMA frag
typedef __attribute__((ext_vector_type(4))) float floatx4;  // f32x4 acc frag

// compiler-only fence: blocks LDS load/store reordering (HW is in-order per wave)
#define MEMBAR() asm volatile("" ::: "memory")

__device__ __forceinline__ float silu_f(float y) { return y / (1.f + expf(-y)); }
__device__ __forceinline__ float bflo(u32 u) { return __uint_as_float(u << 16); }
__device__ __forceinline__ float bfhi(u32 u) { return __uint_as_float(u & 0xffff0000u); }
__device__ __forceinline__ float bf2f(u16 v) { return __uint_as_float((u32)v << 16); }
__device__ __forceinline__ u16 f2bf(float x) {
  u32 u = __float_as_uint(x);
  u += 0x7fffu + ((u >> 16) & 1u);
  return (u16)(u >> 16);
}
__device__ __forceinline__ u32 pack2(float a, float b) {
  return (u32)f2bf(a) | ((u32)f2bf(b) << 16);
}
__device__ __forceinline__ short8 mk8(u32 a, u32 b, u32 c, u32 d) {
  union { u32 u[4]; short8 s; } t;
  t.u[0] = a; t.u[1] = b; t.u[2] = c; t.u[3] = d;
  return t.s;
}
// both shfls executed by all lanes (uniform), then per-lane select
__device__ __forceinline__ u32 shfl_sel(u32 va, u32 vb, int s, bool sel) {
  u32 x = (u32)__shfl((int)va, s);
  u32 y = (u32)__shfl((int)vb, s);
  return sel ? y : x;
}

#define GLDS16(gp, lp)                                           \
  __builtin_amdgcn_global_load_lds(                              \
      (const __attribute__((address_space(1))) void*)(gp),       \
      (__attribute__((address_space(3))) void*)(lp), 16, 0, 0)

// ---------------- unified prep: conv/stem repack + qkv/proj/mlp casts -------
__global__ __launch_bounds__(256) void prep_kernel(
    const float* __restrict__ w_blk, const float* __restrict__ s_blk,
    const float* __restrict__ w_stem, const float* __restrict__ s_stem,
    const float* __restrict__ qkv_w, const float* __restrict__ proj_w,
    const float* __restrict__ mlp_w1, const float* __restrict__ mlp_w2,
    u16* __restrict__ wtc, u16* __restrict__ wts, u16* __restrict__ qwb,
    u16* __restrict__ pwb, u16* __restrict__ m1wb, u16* __restrict__ m2wb) {
  int idx = blockIdx.x * 256 + threadIdx.x;
  if (idx < 147456) {
    int c = idx & 63;
    int rest = idx >> 6;
    int oc = rest & 63;
    int ct = rest >> 6;
    int conv = ct / 9, t = ct % 9;
    float w = w_blk[((size_t)(conv * 64 + oc) * 64 + c) * 9 + t];
    wtc[idx] = f2bf(w * s_blk[conv * 64 + oc]);
  } else if (idx < 163840) {
    int j = idx - 147456;
    int c = j & 127, oc = j >> 7;
    wts[j] = f2bf(w_stem[(size_t)oc * 128 + c] * s_stem[oc]);
  } else if (idx < 360448) {
    int j = idx - 163840;
    qwb[j] = f2bf(qkv_w[j]);
  } else if (idx < 425984) {
    int j = idx - 360448;
    pwb[j] = f2bf(proj_w[j]);
  } else if (idx < 491520) {
    int j = idx - 425984;
    m1wb[j] = f2bf(mlp_w1[j]);
  } else if (idx < 557056) {
    int j = idx - 491520;
    m2wb[j] = f2bf(mlp_w2[j]);
  }
}

// ---------------- continuous position bias MLP -----------------------------
__global__ __launch_bounds__(512) void cpb_mlp_kernel(
    const float* __restrict__ w1, const float* __restrict__ b1,
    const float* __restrict__ w2, float* __restrict__ pre) {
  __shared__ float hb[512];
  int t = blockIdx.x, j = threadIdx.x;
  int i = t / 15, jj = t % 15;
  float c0 = (float)(i - 7) * (8.f / 7.f);
  float c1 = (float)(jj - 7) * (8.f / 7.f);
  float s0 = (c0 > 0.f) ? 1.f : ((c0 < 0.f) ? -1.f : 0.f);
  float s1 = (c1 > 0.f) ? 1.f : ((c1 < 0.f) ? -1.f : 0.f);
  float t0 = s0 * log2f(fabsf(c0) + 1.f) * (1.f / 3.f);
  float t1 = s1 * log2f(fabsf(c1) + 1.f) * (1.f / 3.f);
  float h = t0 * w1[j * 2] + t1 * w1[j * 2 + 1] + b1[j];
  hb[j] = fmaxf(h, 0.f);
  __syncthreads();
  if (j < 8) {
    float s = 0.f;
    for (int k = 0; k < 512; ++k) s += hb[k] * w2[j * 512 + k];
    pre[t * 8 + j] = s;
  }
}

// bias_t[h][m][n]: bias for (key m, query n)
__global__ __launch_bounds__(256) void cpb_expand_kernel(
    const float* __restrict__ pre, float* __restrict__ bias_t) {
  int idx = blockIdx.x * 256 + threadIdx.x;
  int m = idx >> 6, n = idx & 63;
  int di = (n >> 3) - (m >> 3) + 7;
  int dj = (n & 7) - (m & 7) + 7;
  int ti = di * 15 + dj;
#pragma unroll
  for (int h = 0; h < 8; ++h) {
    float v = pre[ti * 8 + h];
    bias_t[h * 4096 + idx] = 16.f / (1.f + expf(-v));
  }
}

// ---------------- x NCHW fp32 -> XT NHWC bf16 -------------------------------
__global__ __launch_bounds__(256) void transpose_in_kernel(
    const float* __restrict__ x, u16* __restrict__ xt) {
  __shared__ float tl[64][65];
  int bid = blockIdx.x;
  int b = bid >> 9;
  int r = bid & 511;
  int cs = r >> 8, hws = r & 255;
  int c0 = cs << 6, hw0 = hws << 6;
  int tid = threadIdx.x;
  for (int e = tid; e < 4096; e += 256) {
    int c = e >> 6, p = e & 63;
    tl[c][p] = x[(size_t)(b * 128 + c0 + c) * HW + hw0 + p];
  }
  __syncthreads();
  for (int e = tid; e < 4096; e += 256) {
    int p = e >> 6, c = e & 63;
    xt[(size_t)(b * HW + hw0 + p) * 128 + c0 + c] = f2bf(tl[c][p]);
  }
}

// ---------------- bf16 MFMA GEMM: C[.,col]=act(A[M,K] @ W[N,K]^T + b) -------
__global__ __launch_bounds__(256, 4) void gemm_bf16_kernel(
    const u16* __restrict__ A, const u16* __restrict__ W,
    const float* __restrict__ bias, u16* __restrict__ C, int K, int ldc,
    int act) {
  __shared__ u16 As[128 * 64];
  __shared__ u16 Ws[64 * 64];
  int tid = threadIdx.x;
  int wv = tid >> 6, lane = tid & 63;
  int m0 = blockIdx.y * 128, n0 = blockIdx.x * 64;
  floatx4 zz = {0.f, 0.f, 0.f, 0.f};
  floatx4 acc[2][4];
#pragma unroll
  for (int i = 0; i < 2; ++i)
#pragma unroll
    for (int j = 0; j < 4; ++j) acc[i][j] = zz;
  int lr = lane >> 3, ls = lane & 7;
  for (int k0 = 0; k0 < K; k0 += 64) {
#pragma unroll
    for (int i = 0; i < 4; ++i) {
      int ci = wv * 4 + i;
      int r = ci * 8 + lr;
      int cc = ls ^ (r & 7);
      GLDS16(A + (size_t)(m0 + r) * K + k0 + cc * 8, As + ci * 512);
    }
#pragma unroll
    for (int i = 0; i < 2; ++i) {
      int ci = wv * 2 + i;
      int r = ci * 8 + lr;
      int cc = ls ^ (r & 7);
      GLDS16(W + (size_t)(n0 + r) * K + k0 + cc * 8, Ws + ci * 512);
    }
    __syncthreads();
#pragma unroll
    for (int kk = 0; kk < 2; ++kk) {
      int g = kk * 4 + (lane >> 4);
      short8 a0, a1, b0, b1, b2, b3;
      {
        int row = wv * 32 + (lane & 15);
        a0 = *(const short8*)&As[row * 64 + (g ^ (row & 7)) * 8];
        int row2 = row + 16;
        a1 = *(const short8*)&As[row2 * 64 + (g ^ (row2 & 7)) * 8];
      }
      {
        int col = lane & 15;
        b0 = *(const short8*)&Ws[col * 64 + (g ^ (col & 7)) * 8];
        int c1 = col + 16;
        b1 = *(const short8*)&Ws[c1 * 64 + (g ^ (c1 & 7)) * 8];
        int c2 = col + 32;
        b2 = *(const short8*)&Ws[c2 * 64 + (g ^ (c2 & 7)) * 8];
        int c3 = col + 48;
        b3 = *(const short8*)&Ws[c3 * 64 + (g ^ (c3 & 7)) * 8];
      }
      acc[0][0] = __builtin_amdgcn_mfma_f32_16x16x32_bf16(a0, b0, acc[0][0], 0, 0, 0);
      acc[0][1] = __builtin_amdgcn_mfma_f32_16x16x32_bf16(a0, b1, acc[0][1], 0, 0, 0);
      acc[0][2] = __builtin_amdgcn_mfma_f32_16x16x32_bf16(a0, b2, acc[0][2], 0, 0, 0);
      acc[0][3] = __builtin_amdgcn_mfma_f32_16x16x32_bf16(a0, b3, acc[0][3], 0, 0, 0);
      acc[1][0] = __builtin_amdgcn_mfma_f32_16x16x32_bf16(a1, b0, acc[1][0], 0, 0, 0);
      acc[1][1] = __builtin_amdgcn_mfma_f32_16x16x32_bf16(a1, b1, acc[1][1], 0, 0, 0);
      acc[1][2] = __builtin_amdgcn_mfma_f32_16x16x32_bf16(a1, b2, acc[1][2], 0, 0, 0);
      acc[1][3] = __builtin_amdgcn_mfma_f32_16x16x32_bf16(a1, b3, acc[1][3], 0, 0, 0);
    }
    __syncthreads();
  }
  int rbase = wv * 32 + ((lane >> 4) << 2);
  int cb = lane & 15;
#pragma unroll
  for (int mi = 0; mi < 2; ++mi) {
#pragma unroll
    for (int nj = 0; nj < 4; ++nj) {
      int col = n0 + nj * 16 + cb;
      float bv = bias[col];
#pragma unroll
      for (int r = 0; r < 4; ++r) {
        int row = m0 + rbase + mi * 16 + r;
        float v = acc[mi][nj][r] + bv;
        if (act == 1) v = 0.5f * v * (1.f + erff(v * 0.70710678118654752f));
        else if (act == 2) v = silu_f(v);
        C[(size_t)row * ldc + col] = f2bf(v);
      }
    }
  }
}

// ---------------- 3x3 conv 64->64 pad1 SiLU, NHWC bf16, implicit MFMA GEMM --
__global__ __launch_bounds__(256) void conv3x3_mfma_kernel(
    const u16* __restrict__ in, int istr, u16* __restrict__ outp, int ostr,
    const u16* __restrict__ wt, const float* __restrict__ bias) {
  __shared__ u16 tile[6400];
  int tid = threadIdx.x;
  int wv = tid >> 6, lane = tid & 63;
  int bx = blockIdx.x, by = blockIdx.y, b = blockIdx.z;
  int h0 = by * 8, w0 = bx * 8;
#pragma unroll
  for (int rr = 0; rr < 4; ++rr) {
    int slot = rr * 256 + tid;
    int p = slot >> 3, ch = slot & 7;
    if (p < 100) {
      int hr = p / 10, hc = p % 10;
      int gh = h0 + hr - 1, gw = w0 + hc - 1;
      bool ok = (gh >= 0) && (gh < 128) && (gw >= 0) && (gw < 128);
      uint4 v = {0u, 0u, 0u, 0u};
      if (ok) {
        size_t pix = (size_t)((b * 128 + gh) * 128 + gw);
        v = *(const uint4*)(in + pix * istr + ch * 8);
      }
      *(uint4*)(tile + p * 64 + ((ch ^ (p & 7)) << 3)) = v;
    }
  }
  __syncthreads();
  int pl = lane & 15;
  int g = lane >> 4;
  int prow = 2 * wv + (pl >> 3), pcol = pl & 7;
  floatx4 zz = {0.f, 0.f, 0.f, 0.f};
  floatx4 acc[4] = {zz, zz, zz, zz};
#pragma unroll
  for (int t = 0; t < 9; ++t) {
    int dy = t / 3, dx = t % 3;
    int hp = (prow + dy) * 10 + (pcol + dx);
    short8 bf0 = *(const short8*)&tile[hp * 64 + (((0 * 4 + g) ^ (hp & 7)) << 3)];
    short8 bf1 = *(const short8*)&tile[hp * 64 + (((1 * 4 + g) ^ (hp & 7)) << 3)];
    const u16* wtap = wt + t * 4096;
#pragma unroll
    for (int nf = 0; nf < 4; ++nf) {
      short8 a0 = *(const short8*)&wtap[(nf * 16 + pl) * 64 + g * 8];
      short8 a1 = *(const short8*)&wtap[(nf * 16 + pl) * 64 + 32 + g * 8];
      acc[nf] = __builtin_amdgcn_mfma_f32_16x16x32_bf16(a0, bf0, acc[nf], 0, 0, 0);
      acc[nf] = __builtin_amdgcn_mfma_f32_16x16x32_bf16(a1, bf1, acc[nf], 0, 0, 0);
    }
  }
  size_t pix = (size_t)((b * 128 + h0 + prow) * 128 + w0 + pcol);
#pragma unroll
  for (int nf = 0; nf < 4; ++nf) {
    float o0 = silu_f(acc[nf][0] + bias[nf * 16 + g * 4 + 0]);
    float o1 = silu_f(acc[nf][1] + bias[nf * 16 + g * 4 + 1]);
    float o2 = silu_f(acc[nf][2] + bias[nf * 16 + g * 4 + 2]);
    float o3 = silu_f(acc[nf][3] + bias[nf * 16 + g * 4 + 3]);
    uint2 w2;
    w2.x = pack2(o0, o1);
    w2.y = pack2(o2, o3);
    *(uint2*)(outp + pix * ostr + nf * 16 + g * 4) = w2;
  }
}

// ---------------- fused qkv-GEMM + window attention v4 ----------------------
// block = 1 window x 8 heads (512 thr, wave = head). E staged once (32KB);
// per-wave 5KB scratch for K/Q transpose, reused as output bounce. V and P
// redistributed in-register via lg-quarter shfl exchange. ONE barrier total.
__device__ __forceinline__ void qkv_mm(const u16* Elds, const u16* qwb,
                                       int moff, int h, int lc, int lg,
                                       floatx4 acc[4][2]) {
  floatx4 zz = {0.f, 0.f, 0.f, 0.f};
#pragma unroll
  for (int mf = 0; mf < 4; ++mf) {
    acc[mf][0] = zz;
    acc[mf][1] = zz;
  }
#pragma unroll
  for (int ks = 0; ks < 8; ++ks) {
    int ch = ks >> 1, g = ((ks & 1) << 2) + lg;
    short8 af[4];
#pragma unroll
    for (int mf = 0; mf < 4; ++mf) {
      int tk = mf * 16 + lc;
      af[mf] = *(const short8*)&Elds[(ch * 64 + tk) * 64 + ((g ^ (tk & 7)) << 3)];
    }
#pragma unroll
    for (int nf = 0; nf < 2; ++nf) {
      short8 bf = *(const short8*)(qwb +
          (size_t)(moff + h * 32 + nf * 16 + lc) * 256 + ks * 32 + lg * 8);
#pragma unroll
      for (int mf = 0; mf < 4; ++mf)
        acc[mf][nf] =
            __builtin_amdgcn_mfma_f32_16x16x32_bf16(af[mf], bf, acc[mf][nf], 0, 0, 0);
    }
  }
}

__global__ __launch_bounds__(512, 4) void attn_fused_kernel(
    const u16* __restrict__ ebf, const u16* __restrict__ qwb,
    const float* __restrict__ qkv_b, const float* __restrict__ logit_scale,
    const float* __restrict__ bias_t, u16* __restrict__ ao) {
  __shared__ __align__(16) char lds[73728];
  int tid = threadIdx.x;
  int w = tid >> 6, l = tid & 63;
  int wid = blockIdx.x;
  int h = __builtin_amdgcn_readfirstlane(w);
  u16* Elds = (u16*)lds;              // [4 chunks][64 rows][64] swizzled (32KB)
  char* Sc = lds + 32768 + w * 5120;  // per-wave scratch; reused as Ol bounce
  char* Ol = Sc;

  int b = wid >> 8, wh = (wid >> 4) & 15, ww = wid & 15;
  int pixbase = (b << 14) + wh * 1024 + ww * 8;
  {  // stage E window once: wave w stages half of chunk w>>1
    int lr = l >> 3, ls = l & 7;
    int ch = w >> 1;
#pragma unroll
    for (int j = 0; j < 4; ++j) {
      int jj = ((w & 1) << 2) + j;
      int pix = pixbase + jj * 128 + lr;
      GLDS16(ebf + (size_t)pix * 256 + ch * 64 + ((ls ^ lr) << 3),
             Elds + (ch * 8 + jj) * 512);
    }
  }
  __syncthreads();  // the ONLY barrier

  int lc = l & 15, lg = l >> 4;
  float scale = __expf(fminf(logit_scale[h], 4.6051701860f));
  floatx4 macc[4][2];
  short8 kf[4], qf[4];

  // ---- K: project, normalize; transpose via scratch -> kf ----
  qkv_mm(Elds, qwb, 256, h, lc, lg, macc);
#pragma unroll
  for (int mf = 0; mf < 4; ++mf)
#pragma unroll
    for (int r = 0; r < 4; ++r) {
      float v0 = macc[mf][0][r], v1 = macc[mf][1][r];
      float ss = v0 * v0 + v1 * v1;
      ss += __shfl_xor(ss, 1);
      ss += __shfl_xor(ss, 2);
      ss += __shfl_xor(ss, 4);
      ss += __shfl_xor(ss, 8);
      float rk = 1.f / fmaxf(sqrtf(ss), 1e-12f);
      int tk = mf * 16 + (lg << 2) + r;
      *(u16*)(Sc + tk * 80 + lc * 2) = f2bf(v0 * rk);
      *(u16*)(Sc + tk * 80 + (16 + lc) * 2) = f2bf(v1 * rk);
    }
  MEMBAR();
#pragma unroll
  for (int i = 0; i < 4; ++i)
    kf[i] = *(const short8*)(Sc + (i * 16 + lc) * 80 + (lg << 4));
  MEMBAR();

  // ---- Q: project+bias, normalize*scale; transpose via scratch -> qf ----
  qkv_mm(Elds, qwb, 0, h, lc, lg, macc);
  {
    float qb0 = qkv_b[h * 32 + lc], qb1 = qkv_b[h * 32 + 16 + lc];
#pragma unroll
    for (int mf = 0; mf < 4; ++mf)
#pragma unroll
      for (int r = 0; r < 4; ++r) {
        float v0 = macc[mf][0][r] + qb0, v1 = macc[mf][1][r] + qb1;
        float ss = v0 * v0 + v1 * v1;
        ss += __shfl_xor(ss, 1);
        ss += __shfl_xor(ss, 2);
        ss += __shfl_xor(ss, 4);
        ss += __shfl_xor(ss, 8);
        float rq = scale / fmaxf(sqrtf(ss), 1e-12f);
        int tk = mf * 16 + (lg << 2) + r;
        *(u16*)(Sc + tk * 80 + lc * 2) = f2bf(v0 * rq);
        *(u16*)(Sc + tk * 80 + (16 + lc) * 2) = f2bf(v1 * rq);
      }
    MEMBAR();
#pragma unroll
    for (int i = 0; i < 4; ++i)
      qf[i] = *(const short8*)(Sc + (i * 16 + lc) * 80 + (lg << 4));
    MEMBAR();
  }

  // ---- V: project + bias, pack bf16 pairs in regs ----
  u32 v01[4][2], v23[4][2];
  qkv_mm(Elds, qwb, 512, h, lc, lg, macc);
  {
    float vb0 = qkv_b[512 + h * 32 + lc], vb1 = qkv_b[512 + h * 32 + 16 + lc];
#pragma unroll
    for (int mf = 0; mf < 4; ++mf) {
      v01[mf][0] = pack2(macc[mf][0][0] + vb0, macc[mf][0][1] + vb0);
      v23[mf][0] = pack2(macc[mf][0][2] + vb0, macc[mf][0][3] + vb0);
      v01[mf][1] = pack2(macc[mf][1][0] + vb1, macc[mf][1][1] + vb1);
      v23[mf][1] = pack2(macc[mf][1][2] + vb1, macc[mf][1][3] + vb1);
    }
  }

  // ---- S^T = Kn @ Qs^T ----
  floatx4 zz = {0.f, 0.f, 0.f, 0.f};
  floatx4 S[4][4];
#pragma unroll
  for (int mi = 0; mi < 4; ++mi)
#pragma unroll
    for (int ni = 0; ni < 4; ++ni)
      S[mi][ni] = __builtin_amdgcn_mfma_f32_16x16x32_bf16(kf[mi], qf[ni], zz, 0, 0, 0);

  const float* bh = bias_t + h * 4096;
  float den[4] = {0.f, 0.f, 0.f, 0.f};
#pragma unroll
  for (int mi = 0; mi < 4; ++mi) {
    int mb = mi * 16 + (lg << 2);
#pragma unroll
    for (int ni = 0; ni < 4; ++ni) {
      int nn = ni * 16 + lc;
#pragma unroll
      for (int r = 0; r < 4; ++r) {
        float e = __expf(S[mi][ni][r] + bh[(mb + r) * 64 + nn]);
        S[mi][ni][r] = e;
        den[ni] += e;
      }
    }
  }
#pragma unroll
  for (int ni = 0; ni < 4; ++ni) {
    den[ni] += __shfl_xor(den[ni], 16);
    den[ni] += __shfl_xor(den[ni], 32);
    den[ni] = 1.f / den[ni];
  }
  // P packs (inv folded): p01/p23[mi][ni] hold rows m=mi*16+lg*4+{0,1}/{2,3}
  u32 p01[4][4], p23[4][4];
#pragma unroll
  for (int mi = 0; mi < 4; ++mi)
#pragma unroll
    for (int ni = 0; ni < 4; ++ni) {
      p01[mi][ni] = pack2(S[mi][ni][0] * den[ni], S[mi][ni][1] * den[ni]);
      p23[mi][ni] = pack2(S[mi][ni][2] * den[ni], S[mi][ni][3] * den[ni]);
    }

  // ---- lg-quarter exchange: build V frags and P frags in-register ----
  int s1 = ((lg & 1) << 5) + lc;  // source lane (lg_s=(lg&1)*2, lc)
  int s2 = s1 + 16;
  bool hi = lg >= 2;              // selects odd mf/mi candidate
  short8 vf[2][2];
#pragma unroll
  for (int ks = 0; ks < 2; ++ks)
#pragma unroll
    for (int db = 0; db < 2; ++db) {
      u32 w0 = shfl_sel(v01[ks * 2][db], v01[ks * 2 + 1][db], s1, hi);
      u32 w1 = shfl_sel(v23[ks * 2][db], v23[ks * 2 + 1][db], s1, hi);
      u32 w2 = shfl_sel(v01[ks * 2][db], v01[ks * 2 + 1][db], s2, hi);
      u32 w3 = shfl_sel(v23[ks * 2][db], v23[ks * 2 + 1][db], s2, hi);
      vf[ks][db] = mk8(w0, w1, w2, w3);
    }
  floatx4 O[4][2];
#pragma unroll
  for (int nb = 0; nb < 4; ++nb) {
    u32 a0 = shfl_sel(p01[0][nb], p01[1][nb], s1, hi);
    u32 a1 = shfl_sel(p23[0][nb], p23[1][nb], s1, hi);
    u32 a2 = shfl_sel(p01[0][nb], p01[1][nb], s2, hi);
    u32 a3 = shfl_sel(p23[0][nb], p23[1][nb], s2, hi);
    short8 pf0 = mk8(a0, a1, a2, a3);
    u32 b0 = shfl_sel(p01[2][nb], p01[3][nb], s1, hi);
    u32 b1 = shfl_sel(p23[2][nb], p23[3][nb], s1, hi);
    u32 b2 = shfl_sel(p01[2][nb], p01[3][nb], s2, hi);
    u32 b3 = shfl_sel(p23[2][nb], p23[3][nb], s2, hi);
    short8 pf1 = mk8(b0, b1, b2, b3);
    floatx4 o0 = __builtin_amdgcn_mfma_f32_16x16x32_bf16(pf0, vf[0][0], zz, 0, 0, 0);
    o0 = __builtin_amdgcn_mfma_f32_16x16x32_bf16(pf1, vf[1][0], o0, 0, 0, 0);
    floatx4 o1 = __builtin_amdgcn_mfma_f32_16x16x32_bf16(pf0, vf[0][1], zz, 0, 0, 0);
    o1 = __builtin_amdgcn_mfma_f32_16x16x32_bf16(pf1, vf[1][1], o1, 0, 0, 0);
    O[nb][0] = o0;
    O[nb][1] = o1;
  }

  // ---- Ol bounce (over per-wave Sc, dead) -> coalesced global store ----
#pragma unroll
  for (int nb = 0; nb < 4; ++nb)
#pragma unroll
    for (int r = 0; r < 4; ++r) {
      int n = nb * 16 + (lg << 2) + r;
      *(u16*)(Ol + n * 72 + lc * 2) = f2bf(O[nb][0][r]);
      *(u16*)(Ol + n * 72 + (16 + lc) * 2) = f2bf(O[nb][1][r]);
    }
  MEMBAR();
  u32 ov[16];
#pragma unroll
  for (int j = 0; j < 16; ++j) ov[j] = *(const u32*)(Ol + l * 72 + j * 4);
  uint4* op = (uint4*)(ao + (size_t)(wid * 64 + l) * 256 + h * 32);
#pragma unroll
  for (int q4 = 0; q4 < 4; ++q4) {
    uint4 v;
    v.x = ov[q4 * 4 + 0];
    v.y = ov[q4 * 4 + 1];
    v.z = ov[q4 * 4 + 2];
    v.w = ov[q4 * 4 + 3];
    op[q4] = v;
  }
}

// ---------------- LN1: SBF = bf16( EBF + LN(P) ), vectorized (R4) -----------
__global__ __launch_bounds__(256) void ln1v_kernel(
    const u16* __restrict__ pin, const u16* __restrict__ ebf,
    u16* __restrict__ sbf, const float* __restrict__ g,
    const float* __restrict__ bb) {
  int tid = threadIdx.x;
  int bid = blockIdx.x;  // 1024 = b(4) x 256 groups of 64 pixels
  int b = bid >> 8, hw0 = (bid & 255) << 6;
  int i = tid >> 2, qq = tid & 3;
  int hw = hw0 + i;
  int him = hw >> 7, wim = hw & 127;
  int wid = b * 256 + (him >> 3) * 16 + (wim >> 3);
  int t = wid * 64 + (him & 7) * 8 + (wim & 7);
  size_t pbase = (size_t)t * 256 + qq * 64;
  size_t ebase = ((size_t)(b * HW + hw)) * 256 + qq * 64;
  float v[64];
  float s1 = 0.f, s2 = 0.f;
#pragma unroll
  for (int j = 0; j < 8; ++j) {
    uint4 u = *(const uint4*)(pin + pbase + j * 8);
    u32 ua[4] = {u.x, u.y, u.z, u.w};
#pragma unroll
    for (int k = 0; k < 4; ++k) {
      float a = bflo(ua[k]), c = bfhi(ua[k]);
      v[j * 8 + 2 * k] = a;
      v[j * 8 + 2 * k + 1] = c;
      s1 += a + c;
      s2 += a * a + c * c;
    }
  }
  s1 += __shfl_xor(s1, 1);
  s1 += __shfl_xor(s1, 2);
  s2 += __shfl_xor(s2, 1);
  s2 += __shfl_xor(s2, 2);
  float mean = s1 * (1.f / 256.f);
  float var = s2 * (1.f / 256.f) - mean * mean;
  float rs = rsqrtf(var + 1e-5f);
#pragma unroll
  for (int j = 0; j < 8; ++j) {
    uint4 u = *(const uint4*)(ebf + ebase + j * 8);
    u32 ua[4] = {u.x, u.y, u.z, u.w};
    uint4 o;
    u32 ow[4];
#pragma unroll
    for (int k = 0; k < 4; ++k) {
      int c = qq * 64 + j * 8 + 2 * k;
      float o0 = bflo(ua[k]) + (v[j * 8 + 2 * k] - mean) * rs * g[c] + bb[c];
      float o1 = bfhi(ua[k]) + (v[j * 8 + 2 * k + 1] - mean) * rs * g[c + 1] + bb[c + 1];
      ow[k] = pack2(o0, o1);
    }
    o.x = ow[0]; o.y = ow[1]; o.z = ow[2]; o.w = ow[3];
    *(uint4*)(sbf + ebase + j * 8) = o;
  }
}

// ---------------- fused mlp2-GEMM (64x256,K=256) + LN2 + residual + NCHW ----
// rows = pixels (no remap). A=Hb, res=SBF, out = NCHW fp32 final output.
__global__ __launch_bounds__(256, 4) void gemm_ln2_kernel(
    const u16* __restrict__ A, const u16* __restrict__ W,
    const float* __restrict__ bias, const float* __restrict__ g,
    const float* __restrict__ bb, const u16* __restrict__ res,
    float* __restrict__ outf) {
  __shared__ __align__(16) char lds[40960];
  u16* As = (u16*)lds;            // [64][64] per k-chunk
  u16* Ws = (u16*)(lds + 8192);   // [256][64]
  u16* Ct = (u16*)lds;            // overlay [64][264]
  int tid = threadIdx.x;
  int w = tid >> 6, l = tid & 63;
  int lr = l >> 3, ls = l & 7;
  int lc = l & 15, lg = l >> 4;
  int m0 = blockIdx.x << 6;
  floatx4 zz = {0.f, 0.f, 0.f, 0.f};
  floatx4 acc[16];
#pragma unroll
  for (int i = 0; i < 16; ++i) acc[i] = zz;
  for (int k0 = 0; k0 < 256; k0 += 64) {
#pragma unroll
    for (int j = 0; j < 2; ++j) {
      int ci = w * 2 + j;
      int r = ci * 8 + lr;
      GLDS16(A + (size_t)(m0 + r) * 256 + k0 + ((ls ^ (r & 7)) << 3),
             As + ci * 512);
    }
#pragma unroll
    for (int j = 0; j < 8; ++j) {
      int ci = w * 8 + j;
      int r = ci * 8 + lr;
      GLDS16(W + (size_t)r * 256 + k0 + ((ls ^ (r & 7)) << 3), Ws + ci * 512);
    }
    __syncthreads();
#pragma unroll
    for (int kk = 0; kk < 2; ++kk) {
      int gg = (kk << 2) + lg;
      int arow = w * 16 + lc;
      short8 af = *(const short8*)&As[arow * 64 + ((gg ^ (arow & 7)) << 3)];
#pragma unroll
      for (int nf = 0; nf < 16; ++nf) {
        int crow = nf * 16 + lc;
        short8 bf = *(const short8*)&Ws[crow * 64 + ((gg ^ (crow & 7)) << 3)];
        acc[nf] = __builtin_amdgcn_mfma_f32_16x16x32_bf16(af, bf, acc[nf], 0, 0, 0);
      }
    }
    __syncthreads();
  }
  // bias + bounce C through LDS (bf16)
#pragma unroll
  for (int nf = 0; nf < 16; ++nf) {
    float bv = bias[nf * 16 + lc];
#pragma unroll
    for (int r = 0; r < 4; ++r)
      Ct[(w * 16 + (lg << 2) + r) * 264 + nf * 16 + lc] = f2bf(acc[nf][r] + bv);
  }
  __syncthreads();
  // LN epilogue: thread = (row i, col-quarter qq); Ct double-read
  int i = tid >> 2, qq = tid & 3;
  float s1 = 0.f, s2 = 0.f;
#pragma unroll
  for (int j2 = 0; j2 < 8; ++j2) {
    uint4 u = *(const uint4*)&Ct[i * 264 + qq * 64 + j2 * 8];
    u32 ua[4] = {u.x, u.y, u.z, u.w};
#pragma unroll
    for (int k = 0; k < 4; ++k) {
      float a = bflo(ua[k]), c = bfhi(ua[k]);
      s1 += a + c;
      s2 += a * a + c * c;
    }
  }
  s1 += __shfl_xor(s1, 1);
  s1 += __shfl_xor(s1, 2);
  s2 += __shfl_xor(s2, 1);
  s2 += __shfl_xor(s2, 2);
  float mean = s1 * (1.f / 256.f);
  float var = s2 * (1.f / 256.f) - mean * mean;
  float rs = rsqrtf(var + 1e-5f);
  int p = m0 + i;
  int b = p >> 14, hw = p & 16383;
  size_t rbase = (size_t)p * 256 + qq * 64;
#pragma unroll
  for (int j2 = 0; j2 < 8; ++j2) {
    uint4 cu = *(const uint4*)&Ct[i * 264 + qq * 64 + j2 * 8];
    u32 ca[4] = {cu.x, cu.y, cu.z, cu.w};
    uint4 u = *(const uint4*)(res + rbase + j2 * 8);
    u32 ua[4] = {u.x, u.y, u.z, u.w};
#pragma unroll
    for (int k = 0; k < 4; ++k) {
      int c = qq * 64 + j2 * 8 + 2 * k;
      float o0 = bflo(ua[k]) + (bflo(ca[k]) - mean) * rs * g[c] + bb[c];
      float o1 = bfhi(ua[k]) + (bfhi(ca[k]) - mean) * rs * g[c + 1] + bb[c + 1];
      outf[(size_t)(b * 256 + c) * HW + hw] = o0;
      outf[(size_t)(b * 256 + c + 1) * HW + hw] = o1;
    }
  }
}

// ---------------------------------------------------------------------------
extern "C" void kernel_launch(void* const* d_in, const int* in_sizes, int n_in,
                              void* d_out, int out_size, void* d_ws, size_t ws_size,
                              hipStream_t stream) {
  const float* x        = (const float*)d_in[0];
  const float* w_stem   = (const float*)d_in[1];
  const float* s_stem   = (const float*)d_in[2];
  const float* b_stem   = (const float*)d_in[3];
  const float* w_blk    = (const float*)d_in[4];
  const float* s_blk    = (const float*)d_in[5];
  const float* b_blk    = (const float*)d_in[6];
  const float* norm1_g  = (const float*)d_in[7];
  const float* norm1_b  = (const float*)d_in[8];
  const float* qkv_w    = (const float*)d_in[9];
  const float* qkv_b    = (const float*)d_in[10];
  const float* proj_w   = (const float*)d_in[11];
  const float* proj_b   = (const float*)d_in[12];
  const float* logit_sc = (const float*)d_in[13];
  const float* cpb_w1   = (const float*)d_in[14];
  const float* cpb_b1   = (const float*)d_in[15];
  const float* cpb_w2   = (const float*)d_in[16];
  const float* norm2_g  = (const float*)d_in[17];
  const float* norm2_b  = (const float*)d_in[18];
  const float* mlp_w1   = (const float*)d_in[19];
  const float* mlp_b1   = (const float*)d_in[20];
  const float* mlp_w2   = (const float*)d_in[21];
  const float* mlp_b2   = (const float*)d_in[22];
  float* out = (float*)d_out;
  float* ws = (float*)d_ws;
  (void)in_sizes; (void)n_in; (void)out_size; (void)ws_size;

  // ---- workspace regions (floats) ----
  float* R0 = ws;                  // 16,777,216
  float* R1 = ws + 16777216;       // 16,777,216
  float* R2 = ws + 33554432;       // 16,777,216
  float* TAIL = ws + 50331648;
  u16* WTC  = (u16*)TAIL;
  u16* WTS  = (u16*)(TAIL + 73728);
  u16* QWB  = (u16*)(TAIL + 81920);
  u16* PWB  = (u16*)(TAIL + 180224);
  u16* M1WB = (u16*)(TAIL + 212992);
  u16* M2WB = (u16*)(TAIL + 245760);
  float* BPRE = TAIL + 278528;
  float* BFT  = TAIL + 280576;

  // phase overlays (R13-verified lifetimes):
  u16* XT  = (u16*)R2;               // dead after stem gemm
  u16* EBF = (u16*)(R2 + 8388608);   // NHWC e; alive until ln1v
  u16* T1  = (u16*)R1;               // conv intermediates
  u16* T2  = (u16*)(R1 + 2097152);
  u16* AO  = (u16*)R0;               // attn out token-major
  u16* P   = (u16*)(R0 + 8388608);   // proj out token-major
  u16* SBF = (u16*)R0;               // S bf16 pixel-major (over dead AO)
  u16* Hb  = (u16*)R2;               // mlp hidden (over dead XT)

  // ---- param prep (one kernel) + CPB ----
  prep_kernel<<<2176, 256, 0, stream>>>(w_blk, s_blk, w_stem, s_stem, qkv_w,
                                        proj_w, mlp_w1, mlp_w2, WTC, WTS, QWB,
                                        PWB, M1WB, M2WB);
  cpb_mlp_kernel<<<225, 512, 0, stream>>>(cpb_w1, cpb_b1, cpb_w2, BPRE);
  cpb_expand_kernel<<<16, 256, 0, stream>>>(BPRE, BFT);

  // ---- input transpose + stem (1x1 conv = GEMM, SiLU) -> EBF ch 128..255 ----
  transpose_in_kernel<<<2048, 256, 0, stream>>>(x, XT);
  dim3 gs(2, 512);
  gemm_bf16_kernel<<<gs, 256, 0, stream>>>(XT, WTS, b_stem, EBF + 128, 128, 256, 2);

  // ---- ELAN 3x3 convs (bf16 MFMA implicit GEMM) ----
  dim3 cgrid(16, 16, 4);
  conv3x3_mfma_kernel<<<cgrid, 256, 0, stream>>>(EBF + 128, 256, T1, 64, WTC, b_blk);
  conv3x3_mfma_kernel<<<cgrid, 256, 0, stream>>>(T1, 64, EBF + 64, 256, WTC + 9 * 4096, b_blk + 64);
  conv3x3_mfma_kernel<<<cgrid, 256, 0, stream>>>(EBF + 64, 256, T2, 64, WTC + 18 * 4096, b_blk + 128);
  conv3x3_mfma_kernel<<<cgrid, 256, 0, stream>>>(T2, 64, EBF, 256, WTC + 27 * 4096, b_blk + 192);

  // ---- fused qkv + window attention v4 (1024 windows x 512 thr) ----
  attn_fused_kernel<<<1024, 512, 0, stream>>>(EBF, QWB, qkv_b, logit_sc, BFT, AO);

  // ---- proj + LN1 (proven pair), MLP1, fused mlp2+LN2+transpose ----
  dim3 g4(4, 512);
  gemm_bf16_kernel<<<g4, 256, 0, stream>>>(AO, PWB, proj_b, P, 256, 256, 0);
  ln1v_kernel<<<1024, 256, 0, stream>>>(P, EBF, SBF, norm1_g, norm1_b);
  gemm_bf16_kernel<<<g4, 256, 0, stream>>>(SBF, M1WB, mlp_b1, Hb, 256, 256, 1);
  gemm_ln2_kernel<<<1024, 256, 0, stream>>>(Hb, M2WB, mlp_b2, norm2_g, norm2_b,
                                            SBF, out);
}